// Round 7
// baseline (176.529 us; speedup 1.0000x reference)
//
#include <hip/hip_runtime.h>
#include <hip/hip_bf16.h>
#include <math.h>

#define N_SAMPLES 32768
#define STEP 256
#define N_FRAMES 128
#define N_COEFFS 257
#define KT 576            // stacked K: 288 (cos/Cre) + 288 (sin/-Cim)
#define NKS 18            // K-steps of 32
#define CPD 16
#define N_RES 32
#define EXPR 4
#define CTRL 128
#define NBN 8
#define PI_F 3.14159265358979323846f

typedef __attribute__((ext_vector_type(8))) short bf16x8;
typedef __attribute__((ext_vector_type(4))) float f32x4;

__device__ __forceinline__ unsigned short f2bf(float x) {
    __hip_bfloat16 h = __float2bfloat16(x);
    return *(unsigned short*)&h;
}

// ---------------------------------------------------------------- K0: per-(re,k) scalar params (P, Z, L2)
__global__ __launch_bounds__(256) void k0_params(const float* __restrict__ amp,
                                                 const float* __restrict__ phase,
                                                 const float* __restrict__ decay,
                                                 float* __restrict__ Pa, float* __restrict__ Za,
                                                 float* __restrict__ L2a) {
    int idx = blockIdx.x * 256 + threadIdx.x;     // 128*576 = 73728
    if (idx >= 128 * KT) return;
    int k  = idx % KT;
    int re = idx / KT;
    int r = re >> 2, e = re & 3;
    int kk = (k < 288) ? k : k - 288;
    float P = 0.f, Z = 0.f, L2v = 0.f;
    if (kk < N_COEFFS) {
        int src = (r * N_COEFFS + kk) * EXPR + e;
        float m  = fabsf(amp[src]) + 1e-12f;
        float ph = tanhf(phase[src]) * PI_F;
        float sg = 1.0f / (1.0f + expf(-decay[src]));
        float d  = 0.5f + 0.45f * sg;
        float wk = (kk == 0 || kk == 256) ? (1.0f / 512.0f) : (2.0f / 512.0f);
        float c  = (k < 288) ? (wk * m * cosf(ph)) : (-wk * m * sinf(ph));
        float sgn = (kk & 1) ? -1.f : 1.f;
        P = c * (d + sgn);
        Z = c * d;
        L2v = log2f(d);
    }
    Pa[idx] = P; Za[idx] = Z; L2a[idx] = L2v;
}

// ---------------------------------------------------------------- K0a: A (twiddles) in MFMA frag order, bf16
__global__ __launch_bounds__(256) void k0a_afrag(__hip_bfloat16* __restrict__ Afrag) {
    int f = blockIdx.x * 256 + threadIdx.x;       // 16*18*64*8 = 147456
    int e = f & 7;
    int l = (f >> 3) & 63;
    int s = (f >> 9) % NKS;
    int ot = f / (NKS * 512);
    int o = ot * 16 + (l & 15);
    int k = s * 32 + ((e >> 2) << 4) + (((l >> 4) & 3) << 2) + (e & 3);
    float v;
    if (k < 288) v = cosf((float)((k * o) & 511) * (2.0f * PI_F / 512.0f));
    else { int kk = k - 288; v = sinf((float)((kk * o) & 511) * (2.0f * PI_F / 512.0f)); }
    Afrag[f] = __float2bfloat16(v);
}

// ---------------------------------------------------------------- K0b: B matrix bf16, frag-order rows
__global__ __launch_bounds__(256) void k0b_bgen(const float* __restrict__ Pa, const float* __restrict__ Za,
                                                const float* __restrict__ L2a,
                                                __hip_bfloat16* __restrict__ Bbf) {
    int f = blockIdx.x * 256 + threadIdx.x;       // 128*18*128*32 = 9437184
    int p = f & 31;
    int j = (f >> 5) & 127;
    int rs = f >> 12;
    int s = rs % NKS;
    int re = rs / NKS;
    int g = p >> 3, e = p & 7;
    int k = s * 32 + ((e >> 2) << 4) + (g << 2) + (e & 3);
    int ix = re * KT + k;
    float val = (j == 0) ? Za[ix] : Pa[ix] * exp2f((float)j * L2a[ix]);
    Bbf[f] = __float2bfloat16(val);
}

// ---------------------------------------------------------------- K1m: MFMA resonance GEMM (256o x 16384n, K=576)
__global__ __launch_bounds__(256) void k1m(const short* __restrict__ Afrag,
                                           const short* __restrict__ Bbf,
                                           float* __restrict__ res_raw,
                                           float* __restrict__ normp) {
    __shared__ short Bs[2][2048];
    __shared__ float red[256];
    int tid = threadIdx.x;
    int l = tid & 63, w = tid >> 6;
    int bid = blockIdx.x;             // 1024
    int x = bid & 7, m = bid >> 3;
    int re = x * 16 + (m >> 3);
    int sub = m & 7;
    int bx = sub >> 1, jb = sub & 1;

    int otile = bx * 4 + w;
    bf16x8 af[NKS];
    #pragma unroll
    for (int s = 0; s < NKS; ++s)
        af[s] = *(const bf16x8*)(Afrag + ((size_t)(otile * NKS + s) * 64 + l) * 8);

    f32x4 acc[4] = {{0.f,0.f,0.f,0.f},{0.f,0.f,0.f,0.f},{0.f,0.f,0.f,0.f},{0.f,0.f,0.f,0.f}};
    const short* Bsrc = Bbf + (size_t)re * (NKS * 4096) + jb * 2048;

    __builtin_amdgcn_global_load_lds(
        (__attribute__((address_space(1))) const void*)(Bsrc + tid * 8),
        (__attribute__((address_space(3))) void*)(&Bs[0][tid * 8]), 16, 0, 0);

    int boff = (l & 15) * 32 + (l >> 4) * 8;
    int cur = 0;
    #pragma unroll
    for (int s = 0; s < NKS; ++s) {
        __syncthreads();
        if (s < NKS - 1)
            __builtin_amdgcn_global_load_lds(
                (__attribute__((address_space(1))) const void*)(Bsrc + (s + 1) * 4096 + tid * 8),
                (__attribute__((address_space(3))) void*)(&Bs[cur ^ 1][tid * 8]), 16, 0, 0);
        const short* bp = &Bs[cur][0];
        #pragma unroll
        for (int jt = 0; jt < 4; ++jt) {
            bf16x8 bf = *(const bf16x8*)(bp + jt * 512 + boff);
            acc[jt] = __builtin_amdgcn_mfma_f32_16x16x32_bf16(af[s], bf, acc[jt], 0, 0, 0);
        }
        cur ^= 1;
    }

    int o0 = otile * 16 + ((l >> 4) & 3) * 4;
    int jbase = jb * 64 + (l & 15);
    float s2 = 0.f;
    #pragma unroll
    for (int jt = 0; jt < 4; ++jt) {
        int j = jbase + jt * 16;
        float4 v = make_float4(acc[jt][0], acc[jt][1], acc[jt][2], acc[jt][3]);
        s2 += v.x * v.x + v.y * v.y + v.z * v.z + v.w * v.w;
        *(float4*)&res_raw[(size_t)re * N_SAMPLES + j * STEP + o0] = v;
    }
    red[tid] = s2;
    __syncthreads();
    for (int st = 128; st > 0; st >>= 1) {
        if (tid < st) red[tid] += red[tid + st];
        __syncthreads();
    }
    if (tid == 0) normp[re * 8 + bx * 2 + jb] = red[0];
}

// ---------------------------------------------------------------- K2: finalize inverse norms
__global__ void k2_fin(const float* __restrict__ normp, float* __restrict__ inv_norm) {
    int t = threadIdx.x;
    if (t >= 128) return;
    float s = 0.f;
    #pragma unroll
    for (int i = 0; i < 8; ++i) s += normp[t * 8 + i];
    inv_norm[t] = 1.0f / (sqrtf(s) + 1e-8f);
}

// ---------------------------------------------------------------- K3 v3: impulse FIR -> Gbf frag order, coalesced-by-row writes
// Gbf layout: [r][e][kt][o 256][p 32]; thread owns one (o) row, iterates frames in p-order pairs.
__global__ __launch_bounds__(256) void k3_impconv(const float* __restrict__ res_raw,
                                                  const float* __restrict__ inv_norm,
                                                  const float* __restrict__ noise,
                                                  unsigned int* __restrict__ Gbf_u) {
    __shared__ float st[2][384];
    __shared__ float imp[128];
    int bid = blockIdx.x;                 // 512, XCD-swizzled on r
    int r  = (bid & 7) * 4 + ((bid >> 3) & 3);
    int t2 = bid >> 5;                    // 0..15
    int e  = t2 & 3;
    int kt = t2 >> 2;
    int tid = threadIdx.x;                // o
    int re = r * 4 + e;
    float inv = inv_norm[re];
    if (tid < 128)
        imp[tid] = (0.54f - 0.46f * cosf((2.0f * PI_F / 128.0f) * (float)tid)) * noise[tid];
    const float* rp = res_raw + (size_t)re * N_SAMPLES;
    size_t rowbase = (((size_t)(r * 4 + e) * 4 + kt) * 256 + tid) * 16;   // uint units

    for (int h = 0; h < 16; ++h) {
        // frames for p-slots 2h, 2h+1: j1 = j0 + 1
        int j0 = ((h >> 1) & 1) * 16 + (h >> 2) * 4 + (h & 1) * 2;
        int jj0 = kt * 32 + j0;
        int gb0 = jj0 * 256 - 127;
        int gb1 = gb0 + 256;
        __syncthreads();                  // st free (also covers imp on h=0)
        for (int ii = tid; ii < 768; ii += 256) {
            int buf = ii / 384, off = ii % 384;
            int g = (buf ? gb1 : gb0) + off;
            st[buf][off] = (g >= 0) ? rp[g] * inv : 0.f;
        }
        __syncthreads();
        float a0 = 0.f, a1 = 0.f;
        #pragma unroll 4
        for (int u = 0; u < 128; ++u) {
            float w = imp[u];
            int idx = tid + 127 - u;
            a0 = fmaf(w, st[0][idx], a0);
            a1 = fmaf(w, st[1][idx], a1);
        }
        Gbf_u[rowbase + h] = (unsigned int)f2bf(a0) | ((unsigned int)f2bf(a1) << 16);
    }
}

// ---------------------------------------------------------------- K4a: routed weights (= before_upsample output)
__global__ __launch_bounds__(256) void k4a_route(const float* __restrict__ control,
                                                 const float* __restrict__ router,
                                                 float* __restrict__ out_w) {
    int idx = blockIdx.x * 256 + threadIdx.x;
    int f  = idx % CTRL;
    int r  = (idx / CTRL) % N_RES;
    int bn = idx / (CTRL * N_RES);
    float s = 0.f;
    #pragma unroll
    for (int c = 0; c < CPD; ++c)
        s += control[(bn * CPD + c) * CTRL + f] * router[c * N_RES + r];
    out_w[idx] = s;
}

// ---------------------------------------------------------------- K4b: softmax over expressions per ctrl frame
__global__ __launch_bounds__(256) void k4b_dfr(const float* __restrict__ defo, float* __restrict__ d_frames) {
    int idx = blockIdx.x * 256 + threadIdx.x;
    if (idx >= NBN * CTRL) return;
    int f = idx % CTRL, bn = idx / CTRL;
    float v[EXPR]; float mx = -1e30f;
    #pragma unroll
    for (int e = 0; e < EXPR; ++e) {
        float xv = defo[(bn * EXPR + e) * CTRL + f] + (e == 0 ? 1.0f : 0.0f);
        v[e] = xv; mx = fmaxf(mx, xv);
    }
    float sum = 0.f;
    #pragma unroll
    for (int e = 0; e < EXPR; ++e) { v[e] = expf(v[e] - mx); sum += v[e]; }
    float inv = 1.0f / sum;
    #pragma unroll
    for (int e = 0; e < EXPR; ++e) d_frames[(bn * EXPR + e) * CTRL + f] = v[e] * inv;
}

// ---------------------------------------------------------------- K4w: Toeplitz W fragments, bf16 frag order
__global__ __launch_bounds__(256) void k4w(const float* __restrict__ out_w,
                                           short* __restrict__ Wf) {
    const int mt_of[20] = {0,1,2,2,3,3,4,4,4,5,5,5,6,6,6,6,7,7,7,7};
    const int kt_of[20] = {0,0,0,1,0,1,0,1,2,0,1,2,0,1,2,3,0,1,2,3};
    int id = blockIdx.x * 256 + threadIdx.x;   // ((r*8+bn)*20+pr)*64 + l ; total 327680
    if (id >= 32 * 8 * 20 * 64) return;
    int l = id & 63;
    int pr = (id >> 6) % 20;
    int rb = id / (64 * 20);
    int bn = rb & 7, r = rb >> 3;
    int mt = mt_of[pr], kt = kt_of[pr];
    int j = mt * 16 + (l & 15);
    int g4 = (l >> 4) & 3;
    const float* wp = out_w + (bn * N_RES + r) * CTRL;
    bf16x8 v;
    #pragma unroll
    for (int ee = 0; ee < 8; ++ee) {
        int f = kt * 32 + ((ee >> 2) << 4) + (g4 << 2) + (ee & 3);
        float val = (j >= f) ? wp[j - f] : 0.f;
        v[ee] = (short)f2bf(val);
    }
    *(bf16x8*)(Wf + (size_t)id * 8) = v;
}

// ---------------------------------------------------------------- K5m: MFMA Toeplitz conv, LDS-staged B, fused epilogue
__global__ __launch_bounds__(256, 2) void k5m(const short* __restrict__ Gbf,
                                              const short* __restrict__ Wf,
                                              const float* __restrict__ dfr,
                                              __hip_bfloat16* __restrict__ xout) {
    const int mt_of[20] = {0,1,2,2,3,3,4,4,4,5,5,5,6,6,6,6,7,7,7,7};
    const int kt_of[20] = {0,0,0,1,0,1,0,1,2,0,1,2,0,1,2,3,0,1,2,3};
    __shared__ __align__(16) short Gs[8192];   // [ekt 16][o 16][p 32] bf16 = 16KB
    __shared__ float dsm[NBN * EXPR * CTRL];   // 16KB
    int tid = threadIdx.x;
    int bid = blockIdx.x;                       // 512 = 16 on x 32 r, XCD-swizzled on r
    int r  = (bid & 7) * 4 + ((bid >> 3) & 3);
    int on = bid >> 5;                          // 0..15, 16-ocol slab

    #pragma unroll
    for (int it = 0; it < 4; ++it) {
        int c = it * 256 + tid;                 // 0..1023 16B-chunks
        int ekt = c >> 6;
        int o = (c >> 2) & 15;
        int h = c & 3;
        const short* src = Gbf + (((size_t)(r * 16 + ekt) * 256 + on * 16 + o) * 32 + h * 8);
        __builtin_amdgcn_global_load_lds(
            (__attribute__((address_space(1))) const void*)src,
            (__attribute__((address_space(3))) void*)(&Gs[c * 8]), 16, 0, 0);
    }
    for (int i = tid; i < NBN * EXPR * CTRL / 4; i += 256)
        ((float4*)dsm)[i] = ((const float4*)dfr)[i];
    __syncthreads();

    int l = tid & 63, w = tid >> 6;             // w = bn-pair index
    int n = l & 15, g4 = l >> 4;
    int ocol = on * 16 + n;
    float co = ((float)ocol + 0.5f) * (1.0f / 256.0f) - 0.5f;

    bf16x8 bfr[4][4];                            // [e][kt]
    #pragma unroll
    for (int e = 0; e < 4; ++e)
        #pragma unroll
        for (int kt = 0; kt < 4; ++kt)
            bfr[e][kt] = *(const bf16x8*)&Gs[(e * 4 + kt) * 512 + n * 32 + g4 * 8];

    for (int bi = 0; bi < 2; ++bi) {
        int bn = w * 2 + bi;
        f32x4 acc[4][8] = {};
        const short* wfb = Wf + ((size_t)((r * 8 + bn) * 20)) * 512 + l * 8;
        #pragma unroll
        for (int pr = 0; pr < 20; ++pr) {
            bf16x8 wv = *(const bf16x8*)(wfb + pr * 512);
            int mt = mt_of[pr], kt = kt_of[pr];
            #pragma unroll
            for (int e = 0; e < 4; ++e)
                acc[e][mt] = __builtin_amdgcn_mfma_f32_16x16x32_bf16(wv, bfr[e][kt], acc[e][mt], 0, 0, 0);
        }
        __hip_bfloat16* xo = xout + (size_t)(bn * N_RES + r) * N_SAMPLES;
        #pragma unroll
        for (int mt = 0; mt < 8; ++mt) {
            #pragma unroll
            for (int q = 0; q < 4; ++q) {
                int j = mt * 16 + g4 * 4 + q;
                float pos = fminf(fmaxf((float)j + co, 0.0f), 127.0f);
                int lo = (int)floorf(pos);
                int hi = min(lo + 1, 127);
                float wg = pos - (float)lo;
                float x = 0.f;
                #pragma unroll
                for (int e = 0; e < 4; ++e) {
                    const float* dp = dsm + (bn * EXPR + e) * CTRL;
                    float de = dp[lo] * (1.0f - wg) + dp[hi] * wg;
                    x = fmaf(de, acc[e][mt][q], x);
                }
                xo[j * STEP + ocol] = __float2bfloat16(x);
            }
        }
    }
}

// ---------------------------------------------------------------- K6: tanh(gain*x) summed over r
__global__ __launch_bounds__(256) void k6_out(const __hip_bfloat16* __restrict__ xin,
                                              const float* __restrict__ gains,
                                              float* __restrict__ out) {
    __shared__ float gabs[N_RES];
    int bid = blockIdx.x;
    int sc = bid & 127, bn = bid >> 7;
    int o = threadIdx.x;
    if (o < N_RES) gabs[o] = fabsf(gains[o]);
    __syncthreads();
    int s = sc * STEP + o;
    float acc = 0.f;
    #pragma unroll 4
    for (int rr = 0; rr < N_RES; ++rr) {
        float xf = __bfloat162float(xin[(size_t)(bn * N_RES + rr) * N_SAMPLES + s]);
        acc += tanhf(xf * gabs[rr]);
    }
    out[bn * N_SAMPLES + s] = acc;
}

// ---------------------------------------------------------------- launch
extern "C" void kernel_launch(void* const* d_in, const int* in_sizes, int n_in,
                              void* d_out, int out_size, void* d_ws, size_t ws_size,
                              hipStream_t stream) {
    const float* control = (const float*)d_in[0];
    const float* defo    = (const float*)d_in[1];
    const float* router  = (const float*)d_in[2];
    const float* gains   = (const float*)d_in[3];
    const float* amp     = (const float*)d_in[4];
    const float* phase   = (const float*)d_in[5];
    const float* decay   = (const float*)d_in[6];
    const float* noise   = (const float*)d_in[7];

    float* out_summed = (float*)d_out;
    float* out_w      = (float*)d_out + NBN * N_SAMPLES;

    // ws layout:
    //  slot0 [0, 18.87MB): Bbf (k0b->k1m). After k1m dead: Gbf bf16 frag-order (8MB, k3->k5m)
    //                      + Wf bf16 (5.25MB at +8MB, k4w->k5m)
    //  slot1 [18.87, 35.65MB): res_raw f32 (k1m->k3); Pa/Za/L2a alias (dead before k1m);
    //                          xout bf16 alias (k5m->k6)
    //  tail: Afrag 294912B, normp 4KB, inv_norm 512B, dfr 16KB
    char* ws = (char*)d_ws;
    const size_t BSZ = (size_t)128 * NKS * 128 * 32 * 2;       // 18,874,368
    const size_t RSZ = (size_t)N_RES * EXPR * N_SAMPLES * 4;   // 16,777,216
    __hip_bfloat16* Bbf = (__hip_bfloat16*)ws;
    short* Gbf = (short*)ws;                                   // 8,388,608 B
    short* Wf  = (short*)(ws + 8388608);                       // 5,242,880 B
    char* slot1 = ws + BSZ;
    float* res_raw = (float*)slot1;
    float* Pa  = (float*)slot1;
    float* Za  = Pa + 128 * KT;
    float* L2a = Za + 128 * KT;
    __hip_bfloat16* xout = (__hip_bfloat16*)slot1;
    char* tail = slot1 + RSZ;
    __hip_bfloat16* Afrag = (__hip_bfloat16*)tail;             // 147456 elts
    float* normp = (float*)(tail + 294912);                    // 1024 floats
    float* inv_norm = normp + 1024;                            // 128 floats
    float* dfr = inv_norm + 128;                               // 4096 floats

    k0_params<<<288, 256, 0, stream>>>(amp, phase, decay, Pa, Za, L2a);
    k0a_afrag<<<576, 256, 0, stream>>>(Afrag);
    k0b_bgen<<<36864, 256, 0, stream>>>(Pa, Za, L2a, Bbf);
    k4a_route<<<(NBN * N_RES * CTRL) / 256, 256, 0, stream>>>(control, router, out_w);
    k4b_dfr<<<(NBN * CTRL + 255) / 256, 256, 0, stream>>>(defo, dfr);
    k1m<<<1024, 256, 0, stream>>>((const short*)Afrag, (const short*)Bbf, res_raw, normp);
    k2_fin<<<1, 128, 0, stream>>>(normp, inv_norm);
    k4w<<<1280, 256, 0, stream>>>(out_w, Wf);
    k3_impconv<<<512, 256, 0, stream>>>(res_raw, inv_norm, noise, (unsigned int*)Gbf);
    k5m<<<512, 256, 0, stream>>>(Gbf, Wf, dfr, xout);
    k6_out<<<NBN * N_FRAMES, 256, 0, stream>>>(xout, gains, out_summed);
}

// Round 8
// 145.397 us; speedup vs baseline: 1.2141x; 1.2141x over previous
//
#include <hip/hip_runtime.h>
#include <hip/hip_bf16.h>
#include <math.h>

#define N_SAMPLES 32768
#define STEP 256
#define N_FRAMES 128
#define N_COEFFS 257
#define KT 576            // stacked K: 288 (cos/Cre) + 288 (sin/-Cim)
#define NKS 18            // K-steps of 32
#define CPD 16
#define N_RES 32
#define EXPR 4
#define CTRL 128
#define NBN 8
#define PI_F 3.14159265358979323846f

typedef __attribute__((ext_vector_type(8))) short bf16x8;
typedef __attribute__((ext_vector_type(4))) float f32x4;

__device__ __forceinline__ unsigned short f2bf(float x) {
    __hip_bfloat16 h = __float2bfloat16(x);
    return *(unsigned short*)&h;
}

// ---------------------------------------------------------------- K0: per-(re,k) scalar params (P, Z, L2)
__global__ __launch_bounds__(256) void k0_params(const float* __restrict__ amp,
                                                 const float* __restrict__ phase,
                                                 const float* __restrict__ decay,
                                                 float* __restrict__ Pa, float* __restrict__ Za,
                                                 float* __restrict__ L2a) {
    int idx = blockIdx.x * 256 + threadIdx.x;     // 128*576 = 73728
    if (idx >= 128 * KT) return;
    int k  = idx % KT;
    int re = idx / KT;
    int r = re >> 2, e = re & 3;
    int kk = (k < 288) ? k : k - 288;
    float P = 0.f, Z = 0.f, L2v = 0.f;
    if (kk < N_COEFFS) {
        int src = (r * N_COEFFS + kk) * EXPR + e;
        float m  = fabsf(amp[src]) + 1e-12f;
        float ph = tanhf(phase[src]) * PI_F;
        float sg = 1.0f / (1.0f + expf(-decay[src]));
        float d  = 0.5f + 0.45f * sg;
        float wk = (kk == 0 || kk == 256) ? (1.0f / 512.0f) : (2.0f / 512.0f);
        float c  = (k < 288) ? (wk * m * cosf(ph)) : (-wk * m * sinf(ph));
        float sgn = (kk & 1) ? -1.f : 1.f;
        P = c * (d + sgn);
        Z = c * d;
        L2v = log2f(d);
    }
    Pa[idx] = P; Za[idx] = Z; L2a[idx] = L2v;
}

// ---------------------------------------------------------------- K0a: A (twiddles) in MFMA frag order, bf16
__global__ __launch_bounds__(256) void k0a_afrag(__hip_bfloat16* __restrict__ Afrag) {
    int f = blockIdx.x * 256 + threadIdx.x;       // 16*18*64*8 = 147456
    int e = f & 7;
    int l = (f >> 3) & 63;
    int s = (f >> 9) % NKS;
    int ot = f / (NKS * 512);
    int o = ot * 16 + (l & 15);
    int k = s * 32 + ((e >> 2) << 4) + (((l >> 4) & 3) << 2) + (e & 3);
    float v;
    if (k < 288) v = cosf((float)((k * o) & 511) * (2.0f * PI_F / 512.0f));
    else { int kk = k - 288; v = sinf((float)((kk * o) & 511) * (2.0f * PI_F / 512.0f)); }
    Afrag[f] = __float2bfloat16(v);
}

// ---------------------------------------------------------------- K0b: B matrix bf16, frag-order rows
__global__ __launch_bounds__(256) void k0b_bgen(const float* __restrict__ Pa, const float* __restrict__ Za,
                                                const float* __restrict__ L2a,
                                                __hip_bfloat16* __restrict__ Bbf) {
    int f = blockIdx.x * 256 + threadIdx.x;       // 128*18*128*32 = 9437184
    int p = f & 31;
    int j = (f >> 5) & 127;
    int rs = f >> 12;
    int s = rs % NKS;
    int re = rs / NKS;
    int g = p >> 3, e = p & 7;
    int k = s * 32 + ((e >> 2) << 4) + (g << 2) + (e & 3);
    int ix = re * KT + k;
    float val = (j == 0) ? Za[ix] : Pa[ix] * exp2f((float)j * L2a[ix]);
    Bbf[f] = __float2bfloat16(val);
}

// ---------------------------------------------------------------- K1m: MFMA resonance GEMM (256o x 16384n, K=576)
__global__ __launch_bounds__(256) void k1m(const short* __restrict__ Afrag,
                                           const short* __restrict__ Bbf,
                                           float* __restrict__ res_raw,
                                           float* __restrict__ normp) {
    __shared__ short Bs[2][2048];
    __shared__ float red[256];
    int tid = threadIdx.x;
    int l = tid & 63, w = tid >> 6;
    int bid = blockIdx.x;             // 1024
    int x = bid & 7, m = bid >> 3;
    int re = x * 16 + (m >> 3);
    int sub = m & 7;
    int bx = sub >> 1, jb = sub & 1;

    int otile = bx * 4 + w;
    bf16x8 af[NKS];
    #pragma unroll
    for (int s = 0; s < NKS; ++s)
        af[s] = *(const bf16x8*)(Afrag + ((size_t)(otile * NKS + s) * 64 + l) * 8);

    f32x4 acc[4] = {{0.f,0.f,0.f,0.f},{0.f,0.f,0.f,0.f},{0.f,0.f,0.f,0.f},{0.f,0.f,0.f,0.f}};
    const short* Bsrc = Bbf + (size_t)re * (NKS * 4096) + jb * 2048;

    __builtin_amdgcn_global_load_lds(
        (__attribute__((address_space(1))) const void*)(Bsrc + tid * 8),
        (__attribute__((address_space(3))) void*)(&Bs[0][tid * 8]), 16, 0, 0);

    int boff = (l & 15) * 32 + (l >> 4) * 8;
    int cur = 0;
    #pragma unroll
    for (int s = 0; s < NKS; ++s) {
        __syncthreads();
        if (s < NKS - 1)
            __builtin_amdgcn_global_load_lds(
                (__attribute__((address_space(1))) const void*)(Bsrc + (s + 1) * 4096 + tid * 8),
                (__attribute__((address_space(3))) void*)(&Bs[cur ^ 1][tid * 8]), 16, 0, 0);
        const short* bp = &Bs[cur][0];
        #pragma unroll
        for (int jt = 0; jt < 4; ++jt) {
            bf16x8 bf = *(const bf16x8*)(bp + jt * 512 + boff);
            acc[jt] = __builtin_amdgcn_mfma_f32_16x16x32_bf16(af[s], bf, acc[jt], 0, 0, 0);
        }
        cur ^= 1;
    }

    int o0 = otile * 16 + ((l >> 4) & 3) * 4;
    int jbase = jb * 64 + (l & 15);
    float s2 = 0.f;
    #pragma unroll
    for (int jt = 0; jt < 4; ++jt) {
        int j = jbase + jt * 16;
        float4 v = make_float4(acc[jt][0], acc[jt][1], acc[jt][2], acc[jt][3]);
        s2 += v.x * v.x + v.y * v.y + v.z * v.z + v.w * v.w;
        *(float4*)&res_raw[(size_t)re * N_SAMPLES + j * STEP + o0] = v;
    }
    red[tid] = s2;
    __syncthreads();
    for (int st = 128; st > 0; st >>= 1) {
        if (tid < st) red[tid] += red[tid + st];
        __syncthreads();
    }
    if (tid == 0) normp[re * 8 + bx * 2 + jb] = red[0];
}

// ---------------------------------------------------------------- K2: finalize inverse norms
__global__ void k2_fin(const float* __restrict__ normp, float* __restrict__ inv_norm) {
    int t = threadIdx.x;
    if (t >= 128) return;
    float s = 0.f;
    #pragma unroll
    for (int i = 0; i < 8; ++i) s += normp[t * 8 + i];
    inv_norm[t] = 1.0f / (sqrtf(s) + 1e-8f);
}

// ---------------------------------------------------------------- K3 v4: single-stage window, sliding-register FIR
// Gbf layout: [r][e][kt][o 256][p 32]; thread owns 4 o-rows x its wave's 8 frames.
__global__ __launch_bounds__(256) void k3_impconv(const float* __restrict__ res_raw,
                                                  const float* __restrict__ inv_norm,
                                                  const float* __restrict__ noise,
                                                  uint4* __restrict__ Gbf_q) {
    __shared__ __align__(16) float st[8320];   // 33,280B window: samples [kt*8192-127, kt*8192+8192)
    __shared__ __align__(16) float imp[128];
    int bid = blockIdx.x;                 // 512, XCD-swizzled on r
    int r  = (bid & 7) * 4 + ((bid >> 3) & 3);
    int t2 = bid >> 5;                    // 0..15
    int e  = t2 & 3;
    int kt = t2 >> 2;
    int tid = threadIdx.x;
    int re = r * 4 + e;
    float inv = inv_norm[re];
    if (tid < 128)
        imp[tid] = (0.54f - 0.46f * cosf((2.0f * PI_F / 128.0f) * (float)tid)) * noise[tid];
    const float* rp = res_raw + (size_t)re * N_SAMPLES;
    int gbase = kt * 8192 - 127;
    for (int i = tid; i < 8320; i += 256) {
        int g = gbase + i;
        st[i] = (g >= 0 && g < N_SAMPLES) ? rp[g] * inv : 0.f;
    }
    __syncthreads();

    int jg = tid >> 6;                    // wave id -> h-quad
    int o0 = (tid & 63) * 4;              // 4 consecutive output samples
    int jl[8];
    #pragma unroll
    for (int hh = 0; hh < 4; ++hh) {
        int h = jg * 4 + hh;
        int j0 = ((h >> 1) & 1) * 16 + (h >> 2) * 4 + (h & 1) * 2;
        jl[2 * hh] = j0;
        jl[2 * hh + 1] = j0 + 1;
    }
    float4 cur[8];
    float acc[8][4] = {};
    #pragma unroll
    for (int w = 0; w < 8; ++w)
        cur[w] = *(const float4*)&st[jl[w] * 256 + o0];

    for (int v = 0; v < 128; v += 4) {
        float4 im = *(const float4*)&imp[124 - v];
        float wt[4] = {im.w, im.z, im.y, im.x};   // wt[k] = imp[127-v-k]
        #pragma unroll
        for (int w = 0; w < 8; ++w) {
            float4 nx = *(const float4*)&st[jl[w] * 256 + o0 + v + 4];
            float win[8] = {cur[w].x, cur[w].y, cur[w].z, cur[w].w, nx.x, nx.y, nx.z, nx.w};
            #pragma unroll
            for (int k = 0; k < 4; ++k)
                #pragma unroll
                for (int d = 0; d < 4; ++d)
                    acc[w][d] = fmaf(wt[k], win[d + k], acc[w][d]);
            cur[w] = nx;
        }
    }

    // frag-order coalesced writes: one uint4 (h-quad jg) per o-row
    size_t rowb = (((size_t)(r * 4 + e) * 4 + kt) * 256 + o0) * 4;   // uint4 units (row = 4 uint4)
    #pragma unroll
    for (int d = 0; d < 4; ++d) {
        uint4 outv;
        outv.x = (unsigned int)f2bf(acc[0][d]) | ((unsigned int)f2bf(acc[1][d]) << 16);
        outv.y = (unsigned int)f2bf(acc[2][d]) | ((unsigned int)f2bf(acc[3][d]) << 16);
        outv.z = (unsigned int)f2bf(acc[4][d]) | ((unsigned int)f2bf(acc[5][d]) << 16);
        outv.w = (unsigned int)f2bf(acc[6][d]) | ((unsigned int)f2bf(acc[7][d]) << 16);
        Gbf_q[rowb + (size_t)d * 4 + jg] = outv;
    }
}

// ---------------------------------------------------------------- K4a: routed weights (= before_upsample output)
__global__ __launch_bounds__(256) void k4a_route(const float* __restrict__ control,
                                                 const float* __restrict__ router,
                                                 float* __restrict__ out_w) {
    int idx = blockIdx.x * 256 + threadIdx.x;
    int f  = idx % CTRL;
    int r  = (idx / CTRL) % N_RES;
    int bn = idx / (CTRL * N_RES);
    float s = 0.f;
    #pragma unroll
    for (int c = 0; c < CPD; ++c)
        s += control[(bn * CPD + c) * CTRL + f] * router[c * N_RES + r];
    out_w[idx] = s;
}

// ---------------------------------------------------------------- K4b: softmax over expressions per ctrl frame
__global__ __launch_bounds__(256) void k4b_dfr(const float* __restrict__ defo, float* __restrict__ d_frames) {
    int idx = blockIdx.x * 256 + threadIdx.x;
    if (idx >= NBN * CTRL) return;
    int f = idx % CTRL, bn = idx / CTRL;
    float v[EXPR]; float mx = -1e30f;
    #pragma unroll
    for (int e = 0; e < EXPR; ++e) {
        float xv = defo[(bn * EXPR + e) * CTRL + f] + (e == 0 ? 1.0f : 0.0f);
        v[e] = xv; mx = fmaxf(mx, xv);
    }
    float sum = 0.f;
    #pragma unroll
    for (int e = 0; e < EXPR; ++e) { v[e] = expf(v[e] - mx); sum += v[e]; }
    float inv = 1.0f / sum;
    #pragma unroll
    for (int e = 0; e < EXPR; ++e) d_frames[(bn * EXPR + e) * CTRL + f] = v[e] * inv;
}

// ---------------------------------------------------------------- K4w: Toeplitz W fragments, bf16 frag order
__global__ __launch_bounds__(256) void k4w(const float* __restrict__ out_w,
                                           short* __restrict__ Wf) {
    const int mt_of[20] = {0,1,2,2,3,3,4,4,4,5,5,5,6,6,6,6,7,7,7,7};
    const int kt_of[20] = {0,0,0,1,0,1,0,1,2,0,1,2,0,1,2,3,0,1,2,3};
    int id = blockIdx.x * 256 + threadIdx.x;   // ((r*8+bn)*20+pr)*64 + l ; total 327680
    if (id >= 32 * 8 * 20 * 64) return;
    int l = id & 63;
    int pr = (id >> 6) % 20;
    int rb = id / (64 * 20);
    int bn = rb & 7, r = rb >> 3;
    int mt = mt_of[pr], kt = kt_of[pr];
    int j = mt * 16 + (l & 15);
    int g4 = (l >> 4) & 3;
    const float* wp = out_w + (bn * N_RES + r) * CTRL;
    bf16x8 v;
    #pragma unroll
    for (int ee = 0; ee < 8; ++ee) {
        int f = kt * 32 + ((ee >> 2) << 4) + (g4 << 2) + (ee & 3);
        float val = (j >= f) ? wp[j - f] : 0.f;
        v[ee] = (short)f2bf(val);
    }
    *(bf16x8*)(Wf + (size_t)id * 8) = v;
}

// ---------------------------------------------------------------- K5m: MFMA Toeplitz conv, LDS-staged B, fused epilogue
__global__ __launch_bounds__(256, 2) void k5m(const short* __restrict__ Gbf,
                                              const short* __restrict__ Wf,
                                              const float* __restrict__ dfr,
                                              __hip_bfloat16* __restrict__ xout) {
    const int mt_of[20] = {0,1,2,2,3,3,4,4,4,5,5,5,6,6,6,6,7,7,7,7};
    const int kt_of[20] = {0,0,0,1,0,1,0,1,2,0,1,2,0,1,2,3,0,1,2,3};
    __shared__ __align__(16) short Gs[8192];   // [ekt 16][o 16][p 32] bf16 = 16KB
    __shared__ float dsm[NBN * EXPR * CTRL];   // 16KB
    int tid = threadIdx.x;
    int bid = blockIdx.x;                       // 512 = 16 on x 32 r, XCD-swizzled on r
    int r  = (bid & 7) * 4 + ((bid >> 3) & 3);
    int on = bid >> 5;                          // 0..15, 16-ocol slab

    #pragma unroll
    for (int it = 0; it < 4; ++it) {
        int c = it * 256 + tid;                 // 0..1023 16B-chunks
        int ekt = c >> 6;
        int o = (c >> 2) & 15;
        int h = c & 3;
        const short* src = Gbf + (((size_t)(r * 16 + ekt) * 256 + on * 16 + o) * 32 + h * 8);
        __builtin_amdgcn_global_load_lds(
            (__attribute__((address_space(1))) const void*)src,
            (__attribute__((address_space(3))) void*)(&Gs[c * 8]), 16, 0, 0);
    }
    for (int i = tid; i < NBN * EXPR * CTRL / 4; i += 256)
        ((float4*)dsm)[i] = ((const float4*)dfr)[i];
    __syncthreads();

    int l = tid & 63, w = tid >> 6;             // w = bn-pair index
    int n = l & 15, g4 = l >> 4;
    int ocol = on * 16 + n;
    float co = ((float)ocol + 0.5f) * (1.0f / 256.0f) - 0.5f;

    bf16x8 bfr[4][4];                            // [e][kt]
    #pragma unroll
    for (int e = 0; e < 4; ++e)
        #pragma unroll
        for (int kt = 0; kt < 4; ++kt)
            bfr[e][kt] = *(const bf16x8*)&Gs[(e * 4 + kt) * 512 + n * 32 + g4 * 8];

    for (int bi = 0; bi < 2; ++bi) {
        int bn = w * 2 + bi;
        f32x4 acc[4][8] = {};
        const short* wfb = Wf + ((size_t)((r * 8 + bn) * 20)) * 512 + l * 8;
        #pragma unroll
        for (int pr = 0; pr < 20; ++pr) {
            bf16x8 wv = *(const bf16x8*)(wfb + pr * 512);
            int mt = mt_of[pr], kt = kt_of[pr];
            #pragma unroll
            for (int e = 0; e < 4; ++e)
                acc[e][mt] = __builtin_amdgcn_mfma_f32_16x16x32_bf16(wv, bfr[e][kt], acc[e][mt], 0, 0, 0);
        }
        __hip_bfloat16* xo = xout + (size_t)(bn * N_RES + r) * N_SAMPLES;
        #pragma unroll
        for (int mt = 0; mt < 8; ++mt) {
            #pragma unroll
            for (int q = 0; q < 4; ++q) {
                int j = mt * 16 + g4 * 4 + q;
                float pos = fminf(fmaxf((float)j + co, 0.0f), 127.0f);
                int lo = (int)floorf(pos);
                int hi = min(lo + 1, 127);
                float wg = pos - (float)lo;
                float x = 0.f;
                #pragma unroll
                for (int e = 0; e < 4; ++e) {
                    const float* dp = dsm + (bn * EXPR + e) * CTRL;
                    float de = dp[lo] * (1.0f - wg) + dp[hi] * wg;
                    x = fmaf(de, acc[e][mt][q], x);
                }
                xo[j * STEP + ocol] = __float2bfloat16(x);
            }
        }
    }
}

// ---------------------------------------------------------------- K6: tanh(gain*x) summed over r
__global__ __launch_bounds__(256) void k6_out(const __hip_bfloat16* __restrict__ xin,
                                              const float* __restrict__ gains,
                                              float* __restrict__ out) {
    __shared__ float gabs[N_RES];
    int bid = blockIdx.x;
    int sc = bid & 127, bn = bid >> 7;
    int o = threadIdx.x;
    if (o < N_RES) gabs[o] = fabsf(gains[o]);
    __syncthreads();
    int s = sc * STEP + o;
    float acc = 0.f;
    #pragma unroll 4
    for (int rr = 0; rr < N_RES; ++rr) {
        float xf = __bfloat162float(xin[(size_t)(bn * N_RES + rr) * N_SAMPLES + s]);
        acc += tanhf(xf * gabs[rr]);
    }
    out[bn * N_SAMPLES + s] = acc;
}

// ---------------------------------------------------------------- launch
extern "C" void kernel_launch(void* const* d_in, const int* in_sizes, int n_in,
                              void* d_out, int out_size, void* d_ws, size_t ws_size,
                              hipStream_t stream) {
    const float* control = (const float*)d_in[0];
    const float* defo    = (const float*)d_in[1];
    const float* router  = (const float*)d_in[2];
    const float* gains   = (const float*)d_in[3];
    const float* amp     = (const float*)d_in[4];
    const float* phase   = (const float*)d_in[5];
    const float* decay   = (const float*)d_in[6];
    const float* noise   = (const float*)d_in[7];

    float* out_summed = (float*)d_out;
    float* out_w      = (float*)d_out + NBN * N_SAMPLES;

    // ws layout:
    //  slot0 [0, 18.87MB): Bbf (k0b->k1m). After k1m dead: Gbf bf16 frag-order (8MB, k3->k5m)
    //                      + Wf bf16 (5.25MB at +8MB, k4w->k5m)
    //  slot1 [18.87, 35.65MB): res_raw f32 (k1m->k3); Pa/Za/L2a alias (dead before k1m);
    //                          xout bf16 alias (k5m->k6)
    //  tail: Afrag 294912B, normp 4KB, inv_norm 512B, dfr 16KB
    char* ws = (char*)d_ws;
    const size_t BSZ = (size_t)128 * NKS * 128 * 32 * 2;       // 18,874,368
    const size_t RSZ = (size_t)N_RES * EXPR * N_SAMPLES * 4;   // 16,777,216
    __hip_bfloat16* Bbf = (__hip_bfloat16*)ws;
    short* Gbf = (short*)ws;                                   // 8,388,608 B
    short* Wf  = (short*)(ws + 8388608);                       // 5,242,880 B
    char* slot1 = ws + BSZ;
    float* res_raw = (float*)slot1;
    float* Pa  = (float*)slot1;
    float* Za  = Pa + 128 * KT;
    float* L2a = Za + 128 * KT;
    __hip_bfloat16* xout = (__hip_bfloat16*)slot1;
    char* tail = slot1 + RSZ;
    __hip_bfloat16* Afrag = (__hip_bfloat16*)tail;             // 147456 elts
    float* normp = (float*)(tail + 294912);                    // 1024 floats
    float* inv_norm = normp + 1024;                            // 128 floats
    float* dfr = inv_norm + 128;                               // 4096 floats

    k0_params<<<288, 256, 0, stream>>>(amp, phase, decay, Pa, Za, L2a);
    k0a_afrag<<<576, 256, 0, stream>>>(Afrag);
    k0b_bgen<<<36864, 256, 0, stream>>>(Pa, Za, L2a, Bbf);
    k4a_route<<<(NBN * N_RES * CTRL) / 256, 256, 0, stream>>>(control, router, out_w);
    k4b_dfr<<<(NBN * CTRL + 255) / 256, 256, 0, stream>>>(defo, dfr);
    k1m<<<1024, 256, 0, stream>>>((const short*)Afrag, (const short*)Bbf, res_raw, normp);
    k2_fin<<<1, 128, 0, stream>>>(normp, inv_norm);
    k4w<<<1280, 256, 0, stream>>>(out_w, Wf);
    k3_impconv<<<512, 256, 0, stream>>>(res_raw, inv_norm, noise, (uint4*)Gbf);
    k5m<<<512, 256, 0, stream>>>(Gbf, Wf, dfr, xout);
    k6_out<<<NBN * N_FRAMES, 256, 0, stream>>>(xout, gains, out_summed);
}

// Round 9
// 129.687 us; speedup vs baseline: 1.3612x; 1.1211x over previous
//
#include <hip/hip_runtime.h>
#include <hip/hip_bf16.h>
#include <math.h>

#define N_SAMPLES 32768
#define STEP 256
#define N_FRAMES 128
#define N_COEFFS 257
#define KT 576            // stacked K: 288 (cos/Cre) + 288 (sin/-Cim)
#define NKS 18            // K-steps of 32
#define CPD 16
#define N_RES 32
#define EXPR 4
#define CTRL 128
#define NBN 8
#define PI_F 3.14159265358979323846f

typedef __attribute__((ext_vector_type(8))) short bf16x8;
typedef __attribute__((ext_vector_type(4))) float f32x4;

__device__ __forceinline__ unsigned short f2bf(float x) {
    __hip_bfloat16 h = __float2bfloat16(x);
    return *(unsigned short*)&h;
}

// ---------------------------------------------------------------- K0: per-(re,k) scalar params (P, Z, L2)
__global__ __launch_bounds__(256) void k0_params(const float* __restrict__ amp,
                                                 const float* __restrict__ phase,
                                                 const float* __restrict__ decay,
                                                 float* __restrict__ Pa, float* __restrict__ Za,
                                                 float* __restrict__ L2a) {
    int idx = blockIdx.x * 256 + threadIdx.x;     // 128*576 = 73728
    if (idx >= 128 * KT) return;
    int k  = idx % KT;
    int re = idx / KT;
    int r = re >> 2, e = re & 3;
    int kk = (k < 288) ? k : k - 288;
    float P = 0.f, Z = 0.f, L2v = 0.f;
    if (kk < N_COEFFS) {
        int src = (r * N_COEFFS + kk) * EXPR + e;
        float m  = fabsf(amp[src]) + 1e-12f;
        float ph = tanhf(phase[src]) * PI_F;
        float sg = 1.0f / (1.0f + expf(-decay[src]));
        float d  = 0.5f + 0.45f * sg;
        float wk = (kk == 0 || kk == 256) ? (1.0f / 512.0f) : (2.0f / 512.0f);
        float c  = (k < 288) ? (wk * m * cosf(ph)) : (-wk * m * sinf(ph));
        float sgn = (kk & 1) ? -1.f : 1.f;
        P = c * (d + sgn);
        Z = c * d;
        L2v = log2f(d);
    }
    Pa[idx] = P; Za[idx] = Z; L2a[idx] = L2v;
}

// ---------------------------------------------------------------- K0a: A (twiddles) in MFMA frag order, bf16
__global__ __launch_bounds__(256) void k0a_afrag(__hip_bfloat16* __restrict__ Afrag) {
    int f = blockIdx.x * 256 + threadIdx.x;       // 16*18*64*8 = 147456
    int e = f & 7;
    int l = (f >> 3) & 63;
    int s = (f >> 9) % NKS;
    int ot = f / (NKS * 512);
    int o = ot * 16 + (l & 15);
    int k = s * 32 + ((e >> 2) << 4) + (((l >> 4) & 3) << 2) + (e & 3);
    float v;
    if (k < 288) v = cosf((float)((k * o) & 511) * (2.0f * PI_F / 512.0f));
    else { int kk = k - 288; v = sinf((float)((kk * o) & 511) * (2.0f * PI_F / 512.0f)); }
    Afrag[f] = __float2bfloat16(v);
}

// ---------------------------------------------------------------- K0b: B matrix bf16, frag-order rows
__global__ __launch_bounds__(256) void k0b_bgen(const float* __restrict__ Pa, const float* __restrict__ Za,
                                                const float* __restrict__ L2a,
                                                __hip_bfloat16* __restrict__ Bbf) {
    int f = blockIdx.x * 256 + threadIdx.x;       // 128*18*128*32 = 9437184
    int p = f & 31;
    int j = (f >> 5) & 127;
    int rs = f >> 12;
    int s = rs % NKS;
    int re = rs / NKS;
    int g = p >> 3, e = p & 7;
    int k = s * 32 + ((e >> 2) << 4) + (g << 2) + (e & 3);
    int ix = re * KT + k;
    float val = (j == 0) ? Za[ix] : Pa[ix] * exp2f((float)j * L2a[ix]);
    Bbf[f] = __float2bfloat16(val);
}

// ---------------------------------------------------------------- K1m: MFMA resonance GEMM (256o x 16384n, K=576)
__global__ __launch_bounds__(256) void k1m(const short* __restrict__ Afrag,
                                           const short* __restrict__ Bbf,
                                           float* __restrict__ res_raw,
                                           float* __restrict__ normp) {
    __shared__ short Bs[2][2048];
    __shared__ float red[256];
    int tid = threadIdx.x;
    int l = tid & 63, w = tid >> 6;
    int bid = blockIdx.x;             // 1024
    int x = bid & 7, m = bid >> 3;
    int re = x * 16 + (m >> 3);
    int sub = m & 7;
    int bx = sub >> 1, jb = sub & 1;

    int otile = bx * 4 + w;
    bf16x8 af[NKS];
    #pragma unroll
    for (int s = 0; s < NKS; ++s)
        af[s] = *(const bf16x8*)(Afrag + ((size_t)(otile * NKS + s) * 64 + l) * 8);

    f32x4 acc[4] = {{0.f,0.f,0.f,0.f},{0.f,0.f,0.f,0.f},{0.f,0.f,0.f,0.f},{0.f,0.f,0.f,0.f}};
    const short* Bsrc = Bbf + (size_t)re * (NKS * 4096) + jb * 2048;

    __builtin_amdgcn_global_load_lds(
        (__attribute__((address_space(1))) const void*)(Bsrc + tid * 8),
        (__attribute__((address_space(3))) void*)(&Bs[0][tid * 8]), 16, 0, 0);

    int boff = (l & 15) * 32 + (l >> 4) * 8;
    int cur = 0;
    #pragma unroll
    for (int s = 0; s < NKS; ++s) {
        __syncthreads();
        if (s < NKS - 1)
            __builtin_amdgcn_global_load_lds(
                (__attribute__((address_space(1))) const void*)(Bsrc + (s + 1) * 4096 + tid * 8),
                (__attribute__((address_space(3))) void*)(&Bs[cur ^ 1][tid * 8]), 16, 0, 0);
        const short* bp = &Bs[cur][0];
        #pragma unroll
        for (int jt = 0; jt < 4; ++jt) {
            bf16x8 bf = *(const bf16x8*)(bp + jt * 512 + boff);
            acc[jt] = __builtin_amdgcn_mfma_f32_16x16x32_bf16(af[s], bf, acc[jt], 0, 0, 0);
        }
        cur ^= 1;
    }

    int o0 = otile * 16 + ((l >> 4) & 3) * 4;
    int jbase = jb * 64 + (l & 15);
    float s2 = 0.f;
    #pragma unroll
    for (int jt = 0; jt < 4; ++jt) {
        int j = jbase + jt * 16;
        float4 v = make_float4(acc[jt][0], acc[jt][1], acc[jt][2], acc[jt][3]);
        s2 += v.x * v.x + v.y * v.y + v.z * v.z + v.w * v.w;
        *(float4*)&res_raw[(size_t)re * N_SAMPLES + j * STEP + o0] = v;
    }
    red[tid] = s2;
    __syncthreads();
    for (int st = 128; st > 0; st >>= 1) {
        if (tid < st) red[tid] += red[tid + st];
        __syncthreads();
    }
    if (tid == 0) normp[re * 8 + bx * 2 + jb] = red[0];
}

// ---------------------------------------------------------------- K2: finalize inverse norms
__global__ void k2_fin(const float* __restrict__ normp, float* __restrict__ inv_norm) {
    int t = threadIdx.x;
    if (t >= 128) return;
    float s = 0.f;
    #pragma unroll
    for (int i = 0; i < 8; ++i) s += normp[t * 8 + i];
    inv_norm[t] = 1.0f / (sqrtf(s) + 1e-8f);
}

// ---------------------------------------------------------------- K3: single-stage window, sliding-register FIR
// Gbf layout: [r][e][kt][o 256][p 32]; thread owns 4 o-rows x its wave's 8 frames.
__global__ __launch_bounds__(256) void k3_impconv(const float* __restrict__ res_raw,
                                                  const float* __restrict__ inv_norm,
                                                  const float* __restrict__ noise,
                                                  uint4* __restrict__ Gbf_q) {
    __shared__ __align__(16) float st[8320];   // window: samples [kt*8192-127, kt*8192+8192)
    __shared__ __align__(16) float imp[128];
    int bid = blockIdx.x;                 // 512, XCD-swizzled on r
    int r  = (bid & 7) * 4 + ((bid >> 3) & 3);
    int t2 = bid >> 5;                    // 0..15
    int e  = t2 & 3;
    int kt = t2 >> 2;
    int tid = threadIdx.x;
    int re = r * 4 + e;
    float inv = inv_norm[re];
    if (tid < 128)
        imp[tid] = (0.54f - 0.46f * cosf((2.0f * PI_F / 128.0f) * (float)tid)) * noise[tid];
    const float* rp = res_raw + (size_t)re * N_SAMPLES;
    int gbase = kt * 8192 - 127;
    for (int i = tid; i < 8320; i += 256) {
        int g = gbase + i;
        st[i] = (g >= 0 && g < N_SAMPLES) ? rp[g] * inv : 0.f;
    }
    __syncthreads();

    int jg = tid >> 6;                    // wave id -> h-quad
    int o0 = (tid & 63) * 4;              // 4 consecutive output samples
    int jl[8];
    #pragma unroll
    for (int hh = 0; hh < 4; ++hh) {
        int h = jg * 4 + hh;
        int j0 = ((h >> 1) & 1) * 16 + (h >> 2) * 4 + (h & 1) * 2;
        jl[2 * hh] = j0;
        jl[2 * hh + 1] = j0 + 1;
    }
    float4 cur[8];
    float acc[8][4] = {};
    #pragma unroll
    for (int w = 0; w < 8; ++w)
        cur[w] = *(const float4*)&st[jl[w] * 256 + o0];

    for (int v = 0; v < 128; v += 4) {
        float4 im = *(const float4*)&imp[124 - v];
        float wt[4] = {im.w, im.z, im.y, im.x};   // wt[k] = imp[127-v-k]
        #pragma unroll
        for (int w = 0; w < 8; ++w) {
            float4 nx = *(const float4*)&st[jl[w] * 256 + o0 + v + 4];
            float win[8] = {cur[w].x, cur[w].y, cur[w].z, cur[w].w, nx.x, nx.y, nx.z, nx.w};
            #pragma unroll
            for (int k = 0; k < 4; ++k)
                #pragma unroll
                for (int d = 0; d < 4; ++d)
                    acc[w][d] = fmaf(wt[k], win[d + k], acc[w][d]);
            cur[w] = nx;
        }
    }

    size_t rowb = (((size_t)(r * 4 + e) * 4 + kt) * 256 + o0) * 4;   // uint4 units
    #pragma unroll
    for (int d = 0; d < 4; ++d) {
        uint4 outv;
        outv.x = (unsigned int)f2bf(acc[0][d]) | ((unsigned int)f2bf(acc[1][d]) << 16);
        outv.y = (unsigned int)f2bf(acc[2][d]) | ((unsigned int)f2bf(acc[3][d]) << 16);
        outv.z = (unsigned int)f2bf(acc[4][d]) | ((unsigned int)f2bf(acc[5][d]) << 16);
        outv.w = (unsigned int)f2bf(acc[6][d]) | ((unsigned int)f2bf(acc[7][d]) << 16);
        Gbf_q[rowb + (size_t)d * 4 + jg] = outv;
    }
}

// ---------------------------------------------------------------- K4a: routed weights (= before_upsample output)
__global__ __launch_bounds__(256) void k4a_route(const float* __restrict__ control,
                                                 const float* __restrict__ router,
                                                 float* __restrict__ out_w) {
    int idx = blockIdx.x * 256 + threadIdx.x;
    int f  = idx % CTRL;
    int r  = (idx / CTRL) % N_RES;
    int bn = idx / (CTRL * N_RES);
    float s = 0.f;
    #pragma unroll
    for (int c = 0; c < CPD; ++c)
        s += control[(bn * CPD + c) * CTRL + f] * router[c * N_RES + r];
    out_w[idx] = s;
}

// ---------------------------------------------------------------- K4b: softmax over expressions per ctrl frame
__global__ __launch_bounds__(256) void k4b_dfr(const float* __restrict__ defo, float* __restrict__ d_frames) {
    int idx = blockIdx.x * 256 + threadIdx.x;
    if (idx >= NBN * CTRL) return;
    int f = idx % CTRL, bn = idx / CTRL;
    float v[EXPR]; float mx = -1e30f;
    #pragma unroll
    for (int e = 0; e < EXPR; ++e) {
        float xv = defo[(bn * EXPR + e) * CTRL + f] + (e == 0 ? 1.0f : 0.0f);
        v[e] = xv; mx = fmaxf(mx, xv);
    }
    float sum = 0.f;
    #pragma unroll
    for (int e = 0; e < EXPR; ++e) { v[e] = expf(v[e] - mx); sum += v[e]; }
    float inv = 1.0f / sum;
    #pragma unroll
    for (int e = 0; e < EXPR; ++e) d_frames[(bn * EXPR + e) * CTRL + f] = v[e] * inv;
}

// ---------------------------------------------------------------- K4w v2: compressed Toeplitz W fragments (8 per r,bn)
// frag(mt,kt) depends only on b = mt-2kt: element = w[b*16 + n - 16*hi - 4*g4 - elo] (or 0 if neg)
__global__ __launch_bounds__(256) void k4w(const float* __restrict__ out_w,
                                           short* __restrict__ Wfb) {
    int id = blockIdx.x * 256 + threadIdx.x;   // (((r*8+bn)*8+b)*64+l), total 131072
    if (id >= 32 * 8 * 8 * 64) return;
    int l = id & 63;
    int b = (id >> 6) & 7;
    int bn = (id >> 9) & 7;
    int r = id >> 12;
    int n = l & 15, g4 = (l >> 4) & 3;
    const float* wp = out_w + (bn * N_RES + r) * CTRL;
    bf16x8 v;
    #pragma unroll
    for (int ee = 0; ee < 8; ++ee) {
        int diff = b * 16 + n - ((ee >> 2) << 4) - (g4 << 2) - (ee & 3);
        float val = (diff >= 0) ? wp[diff] : 0.f;
        v[ee] = (short)f2bf(val);
    }
    *(bf16x8*)(Wfb + (size_t)id * 8) = v;
}

// ---------------------------------------------------------------- K5m v3: MFMA Toeplitz conv, reg A-frags, f32x4 de-lerp,
// xout layout [bn][r][ocol 256][j 128] (j fastest -> uint2 stores, merged sectors)
__global__ __launch_bounds__(256) void k5m(const short* __restrict__ Gbf,
                                           const short* __restrict__ Wfb,
                                           const float* __restrict__ dfr,
                                           __hip_bfloat16* __restrict__ xout) {
    const int mt_of[20] = {0,1,2,2,3,3,4,4,4,5,5,5,6,6,6,6,7,7,7,7};
    const int kt_of[20] = {0,0,0,1,0,1,0,1,2,0,1,2,0,1,2,3,0,1,2,3};
    __shared__ __align__(16) short Gs[8192];       // [ekt 16][o 16][p 32] = 16KB
    __shared__ __align__(16) float tab[4][130][4]; // [bn-local][j+1 guard rows][e] = 8320B
    int tid = threadIdx.x;
    int bid = blockIdx.x;                           // 1024 = r(32, XCD-swz) x on(16) x bnh(2)
    int r   = (bid & 7) * 4 + ((bid >> 3) & 3);
    int rest = bid >> 5;
    int on  = rest & 15;
    int bnh = rest >> 4;

    // ---- stage G tiles (16KB, all e/kt for this (r,on) slab)
    #pragma unroll
    for (int it = 0; it < 4; ++it) {
        int c = it * 256 + tid;
        int ekt = c >> 6;
        int o = (c >> 2) & 15;
        int h = c & 3;
        const short* src = Gbf + (((size_t)(r * 16 + ekt) * 256 + on * 16 + o) * 32 + h * 8);
        __builtin_amdgcn_global_load_lds(
            (__attribute__((address_space(1))) const void*)src,
            (__attribute__((address_space(3))) void*)(&Gs[c * 8]), 16, 0, 0);
    }
    // ---- stage transposed d-table with guard rows: tab[bnl][jj][e] = d[bn][e][clamp(jj-1,0,127)]
    for (int i = tid; i < 4 * 130 * 4; i += 256) {
        int bnl = i / 520;
        int rem = i % 520;
        int jj = rem >> 2, e = rem & 3;
        int js = jj - 1; js = js < 0 ? 0 : (js > 127 ? 127 : js);
        tab[bnl][jj][e] = dfr[(((bnh * 4 + bnl) * 4 + e) * 128) + js];
    }
    __syncthreads();

    int l = tid & 63, w = tid >> 6;
    int bn = bnh * 4 + w;
    int n = l & 15, g4 = l >> 4;
    int ocol = on * 16 + n;
    int c = (on < 8) ? -1 : 0;
    float wg = (((float)ocol + 0.5f) * (1.0f / 256.0f) - 0.5f) - (float)c;

    // ---- B-frags (G) from LDS
    bf16x8 bfr[4][4];                               // [e][kt]
    #pragma unroll
    for (int e = 0; e < 4; ++e)
        #pragma unroll
        for (int kt = 0; kt < 4; ++kt)
            bfr[e][kt] = *(const bf16x8*)&Gs[(e * 4 + kt) * 512 + n * 32 + g4 * 8];

    // ---- A-frags (W, 8 compressed) from global into regs
    bf16x8 wfrag[8];
    const short* wfb = Wfb + (((size_t)(r * 8 + bn) * 8) * 64 + l) * 8;
    #pragma unroll
    for (int b = 0; b < 8; ++b)
        wfrag[b] = *(const bf16x8*)(wfb + (size_t)b * 512);

    f32x4 acc[4][8] = {};
    #pragma unroll
    for (int pr = 0; pr < 20; ++pr) {
        int mt = mt_of[pr], kt = kt_of[pr];
        int b = mt - 2 * kt;
        #pragma unroll
        for (int e = 0; e < 4; ++e)
            acc[e][mt] = __builtin_amdgcn_mfma_f32_16x16x32_bf16(wfrag[b], bfr[e][kt], acc[e][mt], 0, 0, 0);
    }

    // ---- epilogue: vectorized de-lerp + e-sum, j-contiguous uint2 stores
    __hip_bfloat16* xo = xout + ((size_t)(bn * N_RES + r) * 256 + ocol) * 128;
    #pragma unroll
    for (int mt = 0; mt < 8; ++mt) {
        int base = mt * 16 + (g4 << 2) + c + 1;     // tab row for q=0 lo
        f32x4 tv[5];
        #pragma unroll
        for (int q = 0; q < 5; ++q)
            tv[q] = *(const f32x4*)&tab[w][base + q][0];
        unsigned int us[4];
        #pragma unroll
        for (int q = 0; q < 4; ++q) {
            float x = 0.f;
            #pragma unroll
            for (int e = 0; e < 4; ++e) {
                float de = fmaf(wg, tv[q + 1][e] - tv[q][e], tv[q][e]);
                x = fmaf(de, acc[e][mt][q], x);
            }
            us[q] = (unsigned int)f2bf(x);
        }
        uint2 pk;
        pk.x = us[0] | (us[1] << 16);
        pk.y = us[2] | (us[3] << 16);
        *(uint2*)&xo[mt * 16 + (g4 << 2)] = pk;
    }
}

// ---------------------------------------------------------------- K6 v2: tanh(gain*x) summed over r, [bn][r][ocol][j] input
__global__ __launch_bounds__(256) void k6_out(const __hip_bfloat16* __restrict__ xin,
                                              const float* __restrict__ gains,
                                              float* __restrict__ out) {
    __shared__ float gabs[N_RES];
    int bid = blockIdx.x;                 // 256 = bn(8) x oslab(32)
    int bn = bid >> 5, oslab = bid & 31;
    int tid = threadIdx.x;
    int jo = tid & 31;                    // 32 j-quads
    int oc = tid >> 5;                    // 8 ocols
    int ocol = oslab * 8 + oc;
    if (tid < 32) gabs[tid] = fabsf(gains[tid]);
    __syncthreads();
    float acc[4] = {0.f, 0.f, 0.f, 0.f};
    #pragma unroll 4
    for (int r = 0; r < N_RES; ++r) {
        const unsigned int* p = (const unsigned int*)(xin + ((size_t)(bn * N_RES + r) * 256 + ocol) * 128 + jo * 4);
        unsigned int w0 = p[0], w1 = p[1];
        float g = gabs[r];
        unsigned short h0 = (unsigned short)(w0 & 0xffff), h1 = (unsigned short)(w0 >> 16);
        unsigned short h2 = (unsigned short)(w1 & 0xffff), h3 = (unsigned short)(w1 >> 16);
        acc[0] += tanhf(__bfloat162float(*(__hip_bfloat16*)&h0) * g);
        acc[1] += tanhf(__bfloat162float(*(__hip_bfloat16*)&h1) * g);
        acc[2] += tanhf(__bfloat162float(*(__hip_bfloat16*)&h2) * g);
        acc[3] += tanhf(__bfloat162float(*(__hip_bfloat16*)&h3) * g);
    }
    #pragma unroll
    for (int jj = 0; jj < 4; ++jj)
        out[(size_t)bn * N_SAMPLES + (jo * 4 + jj) * 256 + ocol] = acc[jj];
}

// ---------------------------------------------------------------- launch
extern "C" void kernel_launch(void* const* d_in, const int* in_sizes, int n_in,
                              void* d_out, int out_size, void* d_ws, size_t ws_size,
                              hipStream_t stream) {
    const float* control = (const float*)d_in[0];
    const float* defo    = (const float*)d_in[1];
    const float* router  = (const float*)d_in[2];
    const float* gains   = (const float*)d_in[3];
    const float* amp     = (const float*)d_in[4];
    const float* phase   = (const float*)d_in[5];
    const float* decay   = (const float*)d_in[6];
    const float* noise   = (const float*)d_in[7];

    float* out_summed = (float*)d_out;
    float* out_w      = (float*)d_out + NBN * N_SAMPLES;

    // ws layout:
    //  slot0 [0, 18.87MB): Bbf (k0b->k1m). After k1m dead: Gbf (8MB, k3->k5m) + Wfb (2MB at +8MB, k4w->k5m)
    //  slot1 [18.87, 35.65MB): res_raw f32 (k1m->k3); Pa/Za/L2a alias (dead before k1m);
    //                          xout bf16 alias [bn][r][ocol][j] (k5m->k6)
    //  tail: Afrag 294912B, normp 4KB, inv_norm 512B, dfr 16KB
    char* ws = (char*)d_ws;
    const size_t BSZ = (size_t)128 * NKS * 128 * 32 * 2;       // 18,874,368
    const size_t RSZ = (size_t)N_RES * EXPR * N_SAMPLES * 4;   // 16,777,216
    __hip_bfloat16* Bbf = (__hip_bfloat16*)ws;
    short* Gbf = (short*)ws;                                   // 8,388,608 B
    short* Wfb = (short*)(ws + 8388608);                       // 2,097,152 B
    char* slot1 = ws + BSZ;
    float* res_raw = (float*)slot1;
    float* Pa  = (float*)slot1;
    float* Za  = Pa + 128 * KT;
    float* L2a = Za + 128 * KT;
    __hip_bfloat16* xout = (__hip_bfloat16*)slot1;
    char* tail = slot1 + RSZ;
    __hip_bfloat16* Afrag = (__hip_bfloat16*)tail;             // 147456 elts
    float* normp = (float*)(tail + 294912);                    // 1024 floats
    float* inv_norm = normp + 1024;                            // 128 floats
    float* dfr = inv_norm + 128;                               // 4096 floats

    k0_params<<<288, 256, 0, stream>>>(amp, phase, decay, Pa, Za, L2a);
    k0a_afrag<<<576, 256, 0, stream>>>(Afrag);
    k0b_bgen<<<36864, 256, 0, stream>>>(Pa, Za, L2a, Bbf);
    k4a_route<<<(NBN * N_RES * CTRL) / 256, 256, 0, stream>>>(control, router, out_w);
    k4b_dfr<<<(NBN * CTRL + 255) / 256, 256, 0, stream>>>(defo, dfr);
    k1m<<<1024, 256, 0, stream>>>((const short*)Afrag, (const short*)Bbf, res_raw, normp);
    k2_fin<<<1, 128, 0, stream>>>(normp, inv_norm);
    k4w<<<512, 256, 0, stream>>>(out_w, Wfb);
    k3_impconv<<<512, 256, 0, stream>>>(res_raw, inv_norm, noise, (uint4*)Gbf);
    k5m<<<1024, 256, 0, stream>>>(Gbf, Wfb, dfr, xout);
    k6_out<<<256, 256, 0, stream>>>(xout, gains, out_summed);
}

// Round 10
// 112.229 us; speedup vs baseline: 1.5729x; 1.1556x over previous
//
#include <hip/hip_runtime.h>
#include <hip/hip_bf16.h>
#include <math.h>

#define N_SAMPLES 32768
#define STEP 256
#define N_FRAMES 128
#define N_COEFFS 257
#define KT 576            // stacked K: 288 (cos/Cre) + 288 (sin/-Cim)
#define NKS 18            // K-steps of 32
#define CPD 16
#define N_RES 32
#define EXPR 4
#define CTRL 128
#define NBN 8
#define PI_F 3.14159265358979323846f

typedef __attribute__((ext_vector_type(8))) short bf16x8;
typedef __attribute__((ext_vector_type(4))) float f32x4;

__device__ __forceinline__ unsigned short f2bf(float x) {
    __hip_bfloat16 h = __float2bfloat16(x);
    return *(unsigned short*)&h;
}

// ---------------------------------------------------------------- PREP: fused k0_params | k0a | k4a | k4b | k4w
// block roles: [0,288) params ; [288,864) Afrag ; [864,992) route ; [992,996) dfr ; [996,1252) Wfrag
__global__ __launch_bounds__(256) void prep(const float* __restrict__ amp,
                                            const float* __restrict__ phase,
                                            const float* __restrict__ decay,
                                            const float* __restrict__ control,
                                            const float* __restrict__ router,
                                            const float* __restrict__ defo,
                                            float* __restrict__ Pa, float* __restrict__ Za,
                                            float* __restrict__ L2a,
                                            __hip_bfloat16* __restrict__ Afrag,
                                            float* __restrict__ out_w,
                                            float* __restrict__ dfr,
                                            short* __restrict__ Wfb) {
    __shared__ float wrow[CTRL];
    int bid = blockIdx.x;
    int tid = threadIdx.x;

    if (bid < 288) {
        // ---- k0_params: per-(re,k) P, Z, L2
        int idx = bid * 256 + tid;
        if (idx >= 128 * KT) return;
        int k  = idx % KT;
        int re = idx / KT;
        int r = re >> 2, e = re & 3;
        int kk = (k < 288) ? k : k - 288;
        float P = 0.f, Z = 0.f, L2v = 0.f;
        if (kk < N_COEFFS) {
            int src = (r * N_COEFFS + kk) * EXPR + e;
            float m  = fabsf(amp[src]) + 1e-12f;
            float ph = tanhf(phase[src]) * PI_F;
            float sg = 1.0f / (1.0f + expf(-decay[src]));
            float d  = 0.5f + 0.45f * sg;
            float wk = (kk == 0 || kk == 256) ? (1.0f / 512.0f) : (2.0f / 512.0f);
            float c  = (k < 288) ? (wk * m * cosf(ph)) : (-wk * m * sinf(ph));
            float sgn = (kk & 1) ? -1.f : 1.f;
            P = c * (d + sgn);
            Z = c * d;
            L2v = log2f(d);
        }
        Pa[idx] = P; Za[idx] = Z; L2a[idx] = L2v;
    } else if (bid < 864) {
        // ---- k0a: A (twiddles) in MFMA frag order, bf16
        int f = (bid - 288) * 256 + tid;          // 16*18*64*8 = 147456
        int e = f & 7;
        int l = (f >> 3) & 63;
        int s = (f >> 9) % NKS;
        int ot = f / (NKS * 512);
        int o = ot * 16 + (l & 15);
        int k = s * 32 + ((e >> 2) << 4) + (((l >> 4) & 3) << 2) + (e & 3);
        float v;
        if (k < 288) v = cosf((float)((k * o) & 511) * (2.0f * PI_F / 512.0f));
        else { int kk = k - 288; v = sinf((float)((kk * o) & 511) * (2.0f * PI_F / 512.0f)); }
        Afrag[f] = __float2bfloat16(v);
    } else if (bid < 992) {
        // ---- k4a: routed weights (= before_upsample output)
        int idx = (bid - 864) * 256 + tid;        // 32768
        int f  = idx % CTRL;
        int r  = (idx / CTRL) % N_RES;
        int bn = idx / (CTRL * N_RES);
        float s = 0.f;
        #pragma unroll
        for (int c = 0; c < CPD; ++c)
            s += control[(bn * CPD + c) * CTRL + f] * router[c * N_RES + r];
        out_w[idx] = s;
    } else if (bid < 996) {
        // ---- k4b: softmax over expressions per ctrl frame
        int idx = (bid - 992) * 256 + tid;        // 1024
        int f = idx % CTRL, bn = idx / CTRL;
        float v[EXPR]; float mx = -1e30f;
        #pragma unroll
        for (int e = 0; e < EXPR; ++e) {
            float xv = defo[(bn * EXPR + e) * CTRL + f] + (e == 0 ? 1.0f : 0.0f);
            v[e] = xv; mx = fmaxf(mx, xv);
        }
        float sum = 0.f;
        #pragma unroll
        for (int e = 0; e < EXPR; ++e) { v[e] = expf(v[e] - mx); sum += v[e]; }
        float inv = 1.0f / sum;
        #pragma unroll
        for (int e = 0; e < EXPR; ++e) dfr[(bn * EXPR + e) * CTRL + f] = v[e] * inv;
    } else {
        // ---- k4w: compressed Toeplitz W frags; w-row recomputed in-block
        int b2 = bid - 996;                        // 256 = r(32) x bn(8)
        int r = b2 >> 3, bn = b2 & 7;
        if (tid < 128) {
            float s = 0.f;
            #pragma unroll
            for (int c = 0; c < CPD; ++c)
                s += control[(bn * CPD + c) * CTRL + tid] * router[c * N_RES + r];
            wrow[tid] = s;
        }
        __syncthreads();
        #pragma unroll
        for (int h = 0; h < 2; ++h) {
            int idl = h * 256 + tid;               // 0..511
            int b = idl >> 6, l = idl & 63;
            int n = l & 15, g4 = (l >> 4) & 3;
            bf16x8 v;
            #pragma unroll
            for (int ee = 0; ee < 8; ++ee) {
                int diff = b * 16 + n - ((ee >> 2) << 4) - (g4 << 2) - (ee & 3);
                float val = (diff >= 0) ? wrow[diff] : 0.f;
                v[ee] = (short)f2bf(val);
            }
            *(bf16x8*)(Wfb + ((size_t)((r * 8 + bn) * 8 + b) * 64 + l) * 8) = v;
        }
    }
}

// ---------------------------------------------------------------- K1m v2: MFMA resonance GEMM, B generated in LDS
__global__ __launch_bounds__(256) void k1m(const short* __restrict__ Afrag,
                                           const float* __restrict__ Pa,
                                           const float* __restrict__ Za,
                                           const float* __restrict__ L2a,
                                           float* __restrict__ res_raw,
                                           float* __restrict__ normp) {
    __shared__ __align__(16) short Bs[2048];      // 64 j x 32 k bf16 (4KB)
    __shared__ float red[256];
    int tid = threadIdx.x;
    int l = tid & 63, w = tid >> 6;
    int bid = blockIdx.x;             // 1024, XCD-swizzled on re
    int x = bid & 7, m = bid >> 3;
    int re = x * 16 + (m >> 3);
    int sub = m & 7;
    int bx = sub >> 1, jb = sub & 1;

    int otile = bx * 4 + w;
    bf16x8 af[NKS];
    #pragma unroll
    for (int s = 0; s < NKS; ++s)
        af[s] = *(const bf16x8*)(Afrag + ((size_t)(otile * NKS + s) * 64 + l) * 8);

    // B-generation mapping: thread -> (j row, 8-k group)
    int gj = tid >> 2;                // 0..63
    int gg = tid & 3;                 // 0..3
    int jf = jb * 64 + gj;            // full frame index
    float jf_f = (float)jf;
    const float* Pre = Pa  + re * KT;
    const float* Zre = Za  + re * KT;
    const float* Lre = L2a + re * KT;

    f32x4 acc[4] = {{0.f,0.f,0.f,0.f},{0.f,0.f,0.f,0.f},{0.f,0.f,0.f,0.f},{0.f,0.f,0.f,0.f}};
    int boff = (l & 15) * 32 + (l >> 4) * 8;

    #pragma unroll
    for (int s = 0; s < NKS; ++s) {
        int kb = s * 32 + gg * 4;
        f32x4 p0 = *(const f32x4*)&Pre[kb];
        f32x4 p1 = *(const f32x4*)&Pre[kb + 16];
        f32x4 z0 = *(const f32x4*)&Zre[kb];
        f32x4 z1 = *(const f32x4*)&Zre[kb + 16];
        f32x4 l0 = *(const f32x4*)&Lre[kb];
        f32x4 l1 = *(const f32x4*)&Lre[kb + 16];
        bf16x8 vv;
        #pragma unroll
        for (int q = 0; q < 4; ++q) {
            float v0 = (jf == 0) ? z0[q] : p0[q] * exp2f(jf_f * l0[q]);
            float v1 = (jf == 0) ? z1[q] : p1[q] * exp2f(jf_f * l1[q]);
            vv[q]     = (short)f2bf(v0);
            vv[4 + q] = (short)f2bf(v1);
        }
        __syncthreads();              // previous tile's MFMA reads complete
        *(bf16x8*)&Bs[gj * 32 + gg * 8] = vv;    // linear tid*16B -> conflict-free
        __syncthreads();
        #pragma unroll
        for (int jt = 0; jt < 4; ++jt) {
            bf16x8 bf = *(const bf16x8*)&Bs[jt * 512 + boff];
            acc[jt] = __builtin_amdgcn_mfma_f32_16x16x32_bf16(af[s], bf, acc[jt], 0, 0, 0);
        }
    }

    int o0 = otile * 16 + ((l >> 4) & 3) * 4;
    int jbase = jb * 64 + (l & 15);
    float s2 = 0.f;
    #pragma unroll
    for (int jt = 0; jt < 4; ++jt) {
        int j = jbase + jt * 16;
        float4 v = make_float4(acc[jt][0], acc[jt][1], acc[jt][2], acc[jt][3]);
        s2 += v.x * v.x + v.y * v.y + v.z * v.z + v.w * v.w;
        *(float4*)&res_raw[(size_t)re * N_SAMPLES + j * STEP + o0] = v;
    }
    red[tid] = s2;
    __syncthreads();
    for (int st = 128; st > 0; st >>= 1) {
        if (tid < st) red[tid] += red[tid + st];
        __syncthreads();
    }
    if (tid == 0) normp[re * 8 + bx * 2 + jb] = red[0];
}

// ---------------------------------------------------------------- K3: sliding-register FIR (+inline norm finalize)
// Gbf layout: [r][e][kt][o 256][p 32]; thread owns 4 o-rows x its wave's 8 frames.
__global__ __launch_bounds__(256) void k3_impconv(const float* __restrict__ res_raw,
                                                  const float* __restrict__ normp,
                                                  const float* __restrict__ noise,
                                                  uint4* __restrict__ Gbf_q) {
    __shared__ __align__(16) float st[8320];
    __shared__ __align__(16) float imp[128];
    int bid = blockIdx.x;                 // 512, XCD-swizzled on r
    int r  = (bid & 7) * 4 + ((bid >> 3) & 3);
    int t2 = bid >> 5;
    int e  = t2 & 3;
    int kt = t2 >> 2;
    int tid = threadIdx.x;
    int re = r * 4 + e;
    float ns = 0.f;
    #pragma unroll
    for (int i = 0; i < 8; ++i) ns += normp[re * 8 + i];
    float inv = 1.0f / (sqrtf(ns) + 1e-8f);
    if (tid < 128)
        imp[tid] = (0.54f - 0.46f * cosf((2.0f * PI_F / 128.0f) * (float)tid)) * noise[tid];
    const float* rp = res_raw + (size_t)re * N_SAMPLES;
    int gbase = kt * 8192 - 127;
    for (int i = tid; i < 8320; i += 256) {
        int g = gbase + i;
        st[i] = (g >= 0 && g < N_SAMPLES) ? rp[g] * inv : 0.f;
    }
    __syncthreads();

    int jg = tid >> 6;
    int o0 = (tid & 63) * 4;
    int jl[8];
    #pragma unroll
    for (int hh = 0; hh < 4; ++hh) {
        int h = jg * 4 + hh;
        int j0 = ((h >> 1) & 1) * 16 + (h >> 2) * 4 + (h & 1) * 2;
        jl[2 * hh] = j0;
        jl[2 * hh + 1] = j0 + 1;
    }
    float4 cur[8];
    float acc[8][4] = {};
    #pragma unroll
    for (int w = 0; w < 8; ++w)
        cur[w] = *(const float4*)&st[jl[w] * 256 + o0];

    for (int v = 0; v < 128; v += 4) {
        float4 im = *(const float4*)&imp[124 - v];
        float wt[4] = {im.w, im.z, im.y, im.x};
        #pragma unroll
        for (int w = 0; w < 8; ++w) {
            float4 nx = *(const float4*)&st[jl[w] * 256 + o0 + v + 4];
            float win[8] = {cur[w].x, cur[w].y, cur[w].z, cur[w].w, nx.x, nx.y, nx.z, nx.w};
            #pragma unroll
            for (int k = 0; k < 4; ++k)
                #pragma unroll
                for (int d = 0; d < 4; ++d)
                    acc[w][d] = fmaf(wt[k], win[d + k], acc[w][d]);
            cur[w] = nx;
        }
    }

    size_t rowb = (((size_t)(r * 4 + e) * 4 + kt) * 256 + o0) * 4;
    #pragma unroll
    for (int d = 0; d < 4; ++d) {
        uint4 outv;
        outv.x = (unsigned int)f2bf(acc[0][d]) | ((unsigned int)f2bf(acc[1][d]) << 16);
        outv.y = (unsigned int)f2bf(acc[2][d]) | ((unsigned int)f2bf(acc[3][d]) << 16);
        outv.z = (unsigned int)f2bf(acc[4][d]) | ((unsigned int)f2bf(acc[5][d]) << 16);
        outv.w = (unsigned int)f2bf(acc[6][d]) | ((unsigned int)f2bf(acc[7][d]) << 16);
        Gbf_q[rowb + (size_t)d * 4 + jg] = outv;
    }
}

// ---------------------------------------------------------------- K5m: MFMA Toeplitz conv, reg A-frags, f32x4 de-lerp
__global__ __launch_bounds__(256) void k5m(const short* __restrict__ Gbf,
                                           const short* __restrict__ Wfb,
                                           const float* __restrict__ dfr,
                                           __hip_bfloat16* __restrict__ xout) {
    const int mt_of[20] = {0,1,2,2,3,3,4,4,4,5,5,5,6,6,6,6,7,7,7,7};
    const int kt_of[20] = {0,0,0,1,0,1,0,1,2,0,1,2,0,1,2,3,0,1,2,3};
    __shared__ __align__(16) short Gs[8192];
    __shared__ __align__(16) float tab[4][130][4];
    int tid = threadIdx.x;
    int bid = blockIdx.x;                           // 1024 = r(32, XCD-swz) x on(16) x bnh(2)
    int r   = (bid & 7) * 4 + ((bid >> 3) & 3);
    int rest = bid >> 5;
    int on  = rest & 15;
    int bnh = rest >> 4;

    #pragma unroll
    for (int it = 0; it < 4; ++it) {
        int c = it * 256 + tid;
        int ekt = c >> 6;
        int o = (c >> 2) & 15;
        int h = c & 3;
        const short* src = Gbf + (((size_t)(r * 16 + ekt) * 256 + on * 16 + o) * 32 + h * 8);
        __builtin_amdgcn_global_load_lds(
            (__attribute__((address_space(1))) const void*)src,
            (__attribute__((address_space(3))) void*)(&Gs[c * 8]), 16, 0, 0);
    }
    for (int i = tid; i < 4 * 130 * 4; i += 256) {
        int bnl = i / 520;
        int rem = i % 520;
        int jj = rem >> 2, e = rem & 3;
        int js = jj - 1; js = js < 0 ? 0 : (js > 127 ? 127 : js);
        tab[bnl][jj][e] = dfr[(((bnh * 4 + bnl) * 4 + e) * 128) + js];
    }
    __syncthreads();

    int l = tid & 63, w = tid >> 6;
    int bn = bnh * 4 + w;
    int n = l & 15, g4 = l >> 4;
    int ocol = on * 16 + n;
    int c = (on < 8) ? -1 : 0;
    float wg = (((float)ocol + 0.5f) * (1.0f / 256.0f) - 0.5f) - (float)c;

    bf16x8 bfr[4][4];
    #pragma unroll
    for (int e = 0; e < 4; ++e)
        #pragma unroll
        for (int kt = 0; kt < 4; ++kt)
            bfr[e][kt] = *(const bf16x8*)&Gs[(e * 4 + kt) * 512 + n * 32 + g4 * 8];

    bf16x8 wfrag[8];
    const short* wfb = Wfb + (((size_t)(r * 8 + bn) * 8) * 64 + l) * 8;
    #pragma unroll
    for (int b = 0; b < 8; ++b)
        wfrag[b] = *(const bf16x8*)(wfb + (size_t)b * 512);

    f32x4 acc[4][8] = {};
    #pragma unroll
    for (int pr = 0; pr < 20; ++pr) {
        int mt = mt_of[pr], kt = kt_of[pr];
        int b = mt - 2 * kt;
        #pragma unroll
        for (int e = 0; e < 4; ++e)
            acc[e][mt] = __builtin_amdgcn_mfma_f32_16x16x32_bf16(wfrag[b], bfr[e][kt], acc[e][mt], 0, 0, 0);
    }

    __hip_bfloat16* xo = xout + ((size_t)(bn * N_RES + r) * 256 + ocol) * 128;
    #pragma unroll
    for (int mt = 0; mt < 8; ++mt) {
        int base = mt * 16 + (g4 << 2) + c + 1;
        f32x4 tv[5];
        #pragma unroll
        for (int q = 0; q < 5; ++q)
            tv[q] = *(const f32x4*)&tab[w][base + q][0];
        unsigned int us[4];
        #pragma unroll
        for (int q = 0; q < 4; ++q) {
            float xv = 0.f;
            #pragma unroll
            for (int e = 0; e < 4; ++e) {
                float de = fmaf(wg, tv[q + 1][e] - tv[q][e], tv[q][e]);
                xv = fmaf(de, acc[e][mt][q], xv);
            }
            us[q] = (unsigned int)f2bf(xv);
        }
        uint2 pk;
        pk.x = us[0] | (us[1] << 16);
        pk.y = us[2] | (us[3] << 16);
        *(uint2*)&xo[mt * 16 + (g4 << 2)] = pk;
    }
}

// ---------------------------------------------------------------- K6: tanh(gain*x) summed over r, [bn][r][ocol][j] input
__global__ __launch_bounds__(256) void k6_out(const __hip_bfloat16* __restrict__ xin,
                                              const float* __restrict__ gains,
                                              float* __restrict__ out) {
    __shared__ float gabs[N_RES];
    int bid = blockIdx.x;                 // 256 = bn(8) x oslab(32)
    int bn = bid >> 5, oslab = bid & 31;
    int tid = threadIdx.x;
    int jo = tid & 31;
    int oc = tid >> 5;
    int ocol = oslab * 8 + oc;
    if (tid < 32) gabs[tid] = fabsf(gains[tid]);
    __syncthreads();
    float acc[4] = {0.f, 0.f, 0.f, 0.f};
    #pragma unroll 4
    for (int r = 0; r < N_RES; ++r) {
        const unsigned int* p = (const unsigned int*)(xin + ((size_t)(bn * N_RES + r) * 256 + ocol) * 128 + jo * 4);
        unsigned int w0 = p[0], w1 = p[1];
        float g = gabs[r];
        unsigned short h0 = (unsigned short)(w0 & 0xffff), h1 = (unsigned short)(w0 >> 16);
        unsigned short h2 = (unsigned short)(w1 & 0xffff), h3 = (unsigned short)(w1 >> 16);
        acc[0] += tanhf(__bfloat162float(*(__hip_bfloat16*)&h0) * g);
        acc[1] += tanhf(__bfloat162float(*(__hip_bfloat16*)&h1) * g);
        acc[2] += tanhf(__bfloat162float(*(__hip_bfloat16*)&h2) * g);
        acc[3] += tanhf(__bfloat162float(*(__hip_bfloat16*)&h3) * g);
    }
    #pragma unroll
    for (int jj = 0; jj < 4; ++jj)
        out[(size_t)bn * N_SAMPLES + (jo * 4 + jj) * 256 + ocol] = acc[jj];
}

// ---------------------------------------------------------------- launch
extern "C" void kernel_launch(void* const* d_in, const int* in_sizes, int n_in,
                              void* d_out, int out_size, void* d_ws, size_t ws_size,
                              hipStream_t stream) {
    const float* control = (const float*)d_in[0];
    const float* defo    = (const float*)d_in[1];
    const float* router  = (const float*)d_in[2];
    const float* gains   = (const float*)d_in[3];
    const float* amp     = (const float*)d_in[4];
    const float* phase   = (const float*)d_in[5];
    const float* decay   = (const float*)d_in[6];
    const float* noise   = (const float*)d_in[7];

    float* out_summed = (float*)d_out;
    float* out_w      = (float*)d_out + NBN * N_SAMPLES;

    // ws layout (no aliasing conflicts):
    //  [0, 8MB): Gbf (k3->k5m)
    //  [8MB, 10MB): Wfb (prep->k5m)
    //  [10MB, ~11MB): Afrag (288KB) + normp (4KB) + dfr (16KB) + Pa/Za/L2a (3x288KB)
    //  [16MB, 32.8MB): res_raw f32 (k1m->k3); xout bf16 alias (k5m->k6, res_raw dead)
    char* ws = (char*)d_ws;
    short* Gbf = (short*)ws;
    short* Wfb = (short*)(ws + 8388608);
    char* tail = ws + 10485760;
    __hip_bfloat16* Afrag = (__hip_bfloat16*)tail;             // 294912 B
    float* normp = (float*)(tail + 294912);                    // 4096 B
    float* dfr   = (float*)(tail + 294912 + 4096);             // 16384 B
    float* Pa    = (float*)(tail + 294912 + 4096 + 16384);     // 294912 B
    float* Za    = Pa + 128 * KT;
    float* L2a   = Za + 128 * KT;
    char* slot1 = ws + 16777216;
    float* res_raw = (float*)slot1;
    __hip_bfloat16* xout = (__hip_bfloat16*)slot1;

    prep<<<1252, 256, 0, stream>>>(amp, phase, decay, control, router, defo,
                                   Pa, Za, L2a, Afrag, out_w, dfr, Wfb);
    k1m<<<1024, 256, 0, stream>>>((const short*)Afrag, Pa, Za, L2a, res_raw, normp);
    k3_impconv<<<512, 256, 0, stream>>>(res_raw, normp, noise, (uint4*)Gbf);
    k5m<<<1024, 256, 0, stream>>>(Gbf, Wfb, dfr, xout);
    k6_out<<<256, 256, 0, stream>>>(xout, gains, out_summed);
}

// Round 11
// 109.559 us; speedup vs baseline: 1.6113x; 1.0244x over previous
//
#include <hip/hip_runtime.h>
#include <hip/hip_bf16.h>
#include <math.h>

#define N_SAMPLES 32768
#define STEP 256
#define N_FRAMES 128
#define N_COEFFS 257
#define KT 576            // stacked K: 288 (cos/Cre) + 288 (sin/-Cim)
#define NKS 18            // K-steps of 32
#define CPD 16
#define N_RES 32
#define EXPR 4
#define CTRL 128
#define NBN 8
#define PI_F 3.14159265358979323846f

typedef __attribute__((ext_vector_type(8))) short bf16x8;
typedef __attribute__((ext_vector_type(4))) float f32x4;

__device__ __forceinline__ unsigned short f2bf(float x) {
    __hip_bfloat16 h = __float2bfloat16(x);
    return *(unsigned short*)&h;
}

// ---------------------------------------------------------------- K1m v3: self-contained MFMA resonance GEMM
// params -> LDS in-block; twiddles via complex-rotation recurrence; B generated in LDS per K-step.
__global__ __launch_bounds__(256) void k1m(const float* __restrict__ amp,
                                           const float* __restrict__ phase,
                                           const float* __restrict__ decay,
                                           float* __restrict__ res_raw,
                                           float* __restrict__ normp) {
    __shared__ __align__(16) short Bs[2048];      // 64 j x 32 k bf16 (4KB)
    __shared__ __align__(16) float Pl[KT];
    __shared__ __align__(16) float Zl[KT];
    __shared__ __align__(16) float Ll[KT];
    __shared__ float red[256];
    int tid = threadIdx.x;
    int l = tid & 63, w = tid >> 6;
    int bid = blockIdx.x;             // 1024, XCD-swizzled on re
    int x = bid & 7, m = bid >> 3;
    int re = x * 16 + (m >> 3);
    int sub = m & 7;
    int bx = sub >> 1, jb = sub & 1;
    int r = re >> 2, e = re & 3;

    // ---- per-block param compute (each block: its re's 576 params)
    for (int k = tid; k < KT; k += 256) {
        int kk = (k < 288) ? k : k - 288;
        float P = 0.f, Z = 0.f, L2v = 0.f;
        if (kk < N_COEFFS) {
            int src = (r * N_COEFFS + kk) * EXPR + e;
            float mm = fabsf(amp[src]) + 1e-12f;
            float ph = tanhf(phase[src]) * PI_F;
            float sg = 1.0f / (1.0f + expf(-decay[src]));
            float d  = 0.5f + 0.45f * sg;
            float wk = (kk == 0 || kk == 256) ? (1.0f / 512.0f) : (2.0f / 512.0f);
            float c  = (k < 288) ? (wk * mm * cosf(ph)) : (-wk * mm * sinf(ph));
            float sgn = (kk & 1) ? -1.f : 1.f;
            P = c * (d + sgn);
            Z = c * d;
            L2v = log2f(d);
        }
        Pl[k] = P; Zl[k] = Z; Ll[k] = L2v;
    }
    __syncthreads();

    // ---- twiddle recurrence state: theta_t[e] = ((t*32 + delta(e)) * o) mod 512, step rot by 32*o
    int o = (bx * 4 + w) * 16 + (l & 15);
    int g4v = l >> 4;                  // 0..3
    float cb[8], sb[8], cc[8], sc[8];
    #pragma unroll
    for (int ee = 0; ee < 8; ++ee) {
        int delta = ((ee >> 2) << 4) + (g4v << 2) + (ee & 3);
        float ang = (float)((delta * o) & 511) * (2.0f * PI_F / 512.0f);
        sincosf(ang, &sb[ee], &cb[ee]);
        cc[ee] = cb[ee]; sc[ee] = sb[ee];
    }
    float rc, rs;
    {
        float ang = (float)((32 * o) & 511) * (2.0f * PI_F / 512.0f);
        sincosf(ang, &rs, &rc);
    }

    // B-generation mapping: thread -> (j row, 8-k group)
    int gj = tid >> 2;
    int gg = tid & 3;
    int jf = jb * 64 + gj;
    float jf_f = (float)jf;

    f32x4 acc[4] = {{0.f,0.f,0.f,0.f},{0.f,0.f,0.f,0.f},{0.f,0.f,0.f,0.f},{0.f,0.f,0.f,0.f}};
    int boff = (l & 15) * 32 + (l >> 4) * 8;

    #pragma unroll
    for (int s = 0; s < NKS; ++s) {
        if (s == 9) {                  // sin-half: reset to base angles
            #pragma unroll
            for (int ee = 0; ee < 8; ++ee) { cc[ee] = cb[ee]; sc[ee] = sb[ee]; }
        }
        bf16x8 af;
        #pragma unroll
        for (int ee = 0; ee < 8; ++ee)
            af[ee] = (short)f2bf((s < 9) ? cc[ee] : sc[ee]);
        if (s != 8 && s != NKS - 1) {  // rotate for next step in this half
            #pragma unroll
            for (int ee = 0; ee < 8; ++ee) {
                float t = cc[ee] * rc - sc[ee] * rs;
                sc[ee] = fmaf(cc[ee], rs, sc[ee] * rc);
                cc[ee] = t;
            }
        }
        // ---- generate B tile elements (from LDS params)
        int kb = s * 32 + gg * 4;
        f32x4 p0 = *(const f32x4*)&Pl[kb];
        f32x4 p1 = *(const f32x4*)&Pl[kb + 16];
        f32x4 z0 = *(const f32x4*)&Zl[kb];
        f32x4 z1 = *(const f32x4*)&Zl[kb + 16];
        f32x4 l0 = *(const f32x4*)&Ll[kb];
        f32x4 l1 = *(const f32x4*)&Ll[kb + 16];
        bf16x8 vv;
        #pragma unroll
        for (int q = 0; q < 4; ++q) {
            float v0 = (jf == 0) ? z0[q] : p0[q] * exp2f(jf_f * l0[q]);
            float v1 = (jf == 0) ? z1[q] : p1[q] * exp2f(jf_f * l1[q]);
            vv[q]     = (short)f2bf(v0);
            vv[4 + q] = (short)f2bf(v1);
        }
        __syncthreads();              // previous tile's MFMA reads complete
        *(bf16x8*)&Bs[gj * 32 + gg * 8] = vv;
        __syncthreads();
        #pragma unroll
        for (int jt = 0; jt < 4; ++jt) {
            bf16x8 bf = *(const bf16x8*)&Bs[jt * 512 + boff];
            acc[jt] = __builtin_amdgcn_mfma_f32_16x16x32_bf16(af, bf, acc[jt], 0, 0, 0);
        }
    }

    int otile = bx * 4 + w;
    int o0 = otile * 16 + ((l >> 4) & 3) * 4;
    int jbase = jb * 64 + (l & 15);
    float s2 = 0.f;
    #pragma unroll
    for (int jt = 0; jt < 4; ++jt) {
        int j = jbase + jt * 16;
        float4 v = make_float4(acc[jt][0], acc[jt][1], acc[jt][2], acc[jt][3]);
        s2 += v.x * v.x + v.y * v.y + v.z * v.z + v.w * v.w;
        *(float4*)&res_raw[(size_t)re * N_SAMPLES + j * STEP + o0] = v;
    }
    red[tid] = s2;
    __syncthreads();
    for (int st = 128; st > 0; st >>= 1) {
        if (tid < st) red[tid] += red[tid + st];
        __syncthreads();
    }
    if (tid == 0) normp[re * 8 + bx * 2 + jb] = red[0];
}

// ---------------------------------------------------------------- K3: sliding-register FIR (+inline norm finalize)
__global__ __launch_bounds__(256) void k3_impconv(const float* __restrict__ res_raw,
                                                  const float* __restrict__ normp,
                                                  const float* __restrict__ noise,
                                                  uint4* __restrict__ Gbf_q) {
    __shared__ __align__(16) float st[8320];
    __shared__ __align__(16) float imp[128];
    int bid = blockIdx.x;                 // 512, XCD-swizzled on r
    int r  = (bid & 7) * 4 + ((bid >> 3) & 3);
    int t2 = bid >> 5;
    int e  = t2 & 3;
    int kt = t2 >> 2;
    int tid = threadIdx.x;
    int re = r * 4 + e;
    float ns = 0.f;
    #pragma unroll
    for (int i = 0; i < 8; ++i) ns += normp[re * 8 + i];
    float inv = 1.0f / (sqrtf(ns) + 1e-8f);
    if (tid < 128)
        imp[tid] = (0.54f - 0.46f * cosf((2.0f * PI_F / 128.0f) * (float)tid)) * noise[tid];
    const float* rp = res_raw + (size_t)re * N_SAMPLES;
    int gbase = kt * 8192 - 127;
    for (int i = tid; i < 8320; i += 256) {
        int g = gbase + i;
        st[i] = (g >= 0 && g < N_SAMPLES) ? rp[g] * inv : 0.f;
    }
    __syncthreads();

    int jg = tid >> 6;
    int o0 = (tid & 63) * 4;
    int jl[8];
    #pragma unroll
    for (int hh = 0; hh < 4; ++hh) {
        int h = jg * 4 + hh;
        int j0 = ((h >> 1) & 1) * 16 + (h >> 2) * 4 + (h & 1) * 2;
        jl[2 * hh] = j0;
        jl[2 * hh + 1] = j0 + 1;
    }
    float4 cur[8];
    float acc[8][4] = {};
    #pragma unroll
    for (int w = 0; w < 8; ++w)
        cur[w] = *(const float4*)&st[jl[w] * 256 + o0];

    for (int v = 0; v < 128; v += 4) {
        float4 im = *(const float4*)&imp[124 - v];
        float wt[4] = {im.w, im.z, im.y, im.x};
        #pragma unroll
        for (int w = 0; w < 8; ++w) {
            float4 nx = *(const float4*)&st[jl[w] * 256 + o0 + v + 4];
            float win[8] = {cur[w].x, cur[w].y, cur[w].z, cur[w].w, nx.x, nx.y, nx.z, nx.w};
            #pragma unroll
            for (int k = 0; k < 4; ++k)
                #pragma unroll
                for (int d = 0; d < 4; ++d)
                    acc[w][d] = fmaf(wt[k], win[d + k], acc[w][d]);
            cur[w] = nx;
        }
    }

    size_t rowb = (((size_t)(r * 4 + e) * 4 + kt) * 256 + o0) * 4;
    #pragma unroll
    for (int d = 0; d < 4; ++d) {
        uint4 outv;
        outv.x = (unsigned int)f2bf(acc[0][d]) | ((unsigned int)f2bf(acc[1][d]) << 16);
        outv.y = (unsigned int)f2bf(acc[2][d]) | ((unsigned int)f2bf(acc[3][d]) << 16);
        outv.z = (unsigned int)f2bf(acc[4][d]) | ((unsigned int)f2bf(acc[5][d]) << 16);
        outv.w = (unsigned int)f2bf(acc[6][d]) | ((unsigned int)f2bf(acc[7][d]) << 16);
        Gbf_q[rowb + (size_t)d * 4 + jg] = outv;
    }
}

// ---------------------------------------------------------------- K5m v4: self-contained MFMA Toeplitz conv
// W-row + wfrag + softmax-tab generated in-block; G staged via global_load_lds.
__global__ __launch_bounds__(256) void k5m(const short* __restrict__ Gbf,
                                           const float* __restrict__ control,
                                           const float* __restrict__ router,
                                           const float* __restrict__ defo,
                                           __hip_bfloat16* __restrict__ xout) {
    const int mt_of[20] = {0,1,2,2,3,3,4,4,4,5,5,5,6,6,6,6,7,7,7,7};
    const int kt_of[20] = {0,0,0,1,0,1,0,1,2,0,1,2,0,1,2,3,0,1,2,3};
    __shared__ __align__(16) short Gs[8192];       // 16KB
    __shared__ __align__(16) float tab[4][130][4]; // 8320B
    __shared__ __align__(16) float wrow[4][128];   // 2KB
    int tid = threadIdx.x;
    int bid = blockIdx.x;                           // 1024 = r(32, XCD-swz) x on(16) x bnh(2)
    int r   = (bid & 7) * 4 + ((bid >> 3) & 3);
    int rest = bid >> 5;
    int on  = rest & 15;
    int bnh = rest >> 4;

    // ---- stage G tiles
    #pragma unroll
    for (int it = 0; it < 4; ++it) {
        int c = it * 256 + tid;
        int ekt = c >> 6;
        int o = (c >> 2) & 15;
        int h = c & 3;
        const short* src = Gbf + (((size_t)(r * 16 + ekt) * 256 + on * 16 + o) * 32 + h * 8);
        __builtin_amdgcn_global_load_lds(
            (__attribute__((address_space(1))) const void*)src,
            (__attribute__((address_space(3))) void*)(&Gs[c * 8]), 16, 0, 0);
    }
    // ---- W rows for this bn-half (4 bn x 128 f)
    for (int i = tid; i < 512; i += 256) {
        int bnl = i >> 7, f = i & 127;
        int bn = bnh * 4 + bnl;
        float s = 0.f;
        #pragma unroll
        for (int c = 0; c < CPD; ++c)
            s += control[(bn * CPD + c) * CTRL + f] * router[c * N_RES + r];
        wrow[bnl][f] = s;
    }
    // ---- softmax tab (direct from defo), rows 1..128
    for (int i = tid; i < 512; i += 256) {
        int bnl = i >> 7, f = i & 127;
        int bn = bnh * 4 + bnl;
        float v[EXPR]; float mx = -1e30f;
        #pragma unroll
        for (int e = 0; e < EXPR; ++e) {
            float xv = defo[(bn * EXPR + e) * CTRL + f] + (e == 0 ? 1.0f : 0.0f);
            v[e] = xv; mx = fmaxf(mx, xv);
        }
        float sum = 0.f;
        #pragma unroll
        for (int e = 0; e < EXPR; ++e) { v[e] = expf(v[e] - mx); sum += v[e]; }
        float is = 1.0f / sum;
        f32x4 tv = {v[0] * is, v[1] * is, v[2] * is, v[3] * is};
        *(f32x4*)&tab[bnl][f + 1][0] = tv;
    }
    // ---- guard rows (recompute softmax at f=0 / f=127)
    if (tid < 8) {
        int bnl = tid & 3, hi = tid >> 2;
        int bn = bnh * 4 + bnl;
        int f = hi ? 127 : 0;
        int jj = hi ? 129 : 0;
        float v[EXPR]; float mx = -1e30f;
        #pragma unroll
        for (int e = 0; e < EXPR; ++e) {
            float xv = defo[(bn * EXPR + e) * CTRL + f] + (e == 0 ? 1.0f : 0.0f);
            v[e] = xv; mx = fmaxf(mx, xv);
        }
        float sum = 0.f;
        #pragma unroll
        for (int e = 0; e < EXPR; ++e) { v[e] = expf(v[e] - mx); sum += v[e]; }
        float is = 1.0f / sum;
        f32x4 tv = {v[0] * is, v[1] * is, v[2] * is, v[3] * is};
        *(f32x4*)&tab[bnl][jj][0] = tv;
    }
    __syncthreads();

    int l = tid & 63, w = tid >> 6;
    int bn = bnh * 4 + w;
    int n = l & 15, g4 = l >> 4;
    int ocol = on * 16 + n;
    int c = (on < 8) ? -1 : 0;
    float wg = (((float)ocol + 0.5f) * (1.0f / 256.0f) - 0.5f) - (float)c;

    bf16x8 bfr[4][4];
    #pragma unroll
    for (int e = 0; e < 4; ++e)
        #pragma unroll
        for (int kt = 0; kt < 4; ++kt)
            bfr[e][kt] = *(const bf16x8*)&Gs[(e * 4 + kt) * 512 + n * 32 + g4 * 8];

    // ---- wfrag from LDS wrow (compressed Toeplitz: b = mt - 2kt)
    bf16x8 wfrag[8];
    #pragma unroll
    for (int b = 0; b < 8; ++b) {
        bf16x8 v;
        #pragma unroll
        for (int ee = 0; ee < 8; ++ee) {
            int diff = b * 16 + n - ((ee >> 2) << 4) - (g4 << 2) - (ee & 3);
            float val = (diff >= 0) ? wrow[w][diff] : 0.f;
            v[ee] = (short)f2bf(val);
        }
        wfrag[b] = v;
    }

    f32x4 acc[4][8] = {};
    #pragma unroll
    for (int pr = 0; pr < 20; ++pr) {
        int mt = mt_of[pr], kt = kt_of[pr];
        int b = mt - 2 * kt;
        #pragma unroll
        for (int e = 0; e < 4; ++e)
            acc[e][mt] = __builtin_amdgcn_mfma_f32_16x16x32_bf16(wfrag[b], bfr[e][kt], acc[e][mt], 0, 0, 0);
    }

    __hip_bfloat16* xo = xout + ((size_t)(bn * N_RES + r) * 256 + ocol) * 128;
    #pragma unroll
    for (int mt = 0; mt < 8; ++mt) {
        int base = mt * 16 + (g4 << 2) + c + 1;
        f32x4 tv[5];
        #pragma unroll
        for (int q = 0; q < 5; ++q)
            tv[q] = *(const f32x4*)&tab[w][base + q][0];
        unsigned int us[4];
        #pragma unroll
        for (int q = 0; q < 4; ++q) {
            float xv = 0.f;
            #pragma unroll
            for (int e = 0; e < 4; ++e) {
                float de = fmaf(wg, tv[q + 1][e] - tv[q][e], tv[q][e]);
                xv = fmaf(de, acc[e][mt][q], xv);
            }
            us[q] = (unsigned int)f2bf(xv);
        }
        uint2 pk;
        pk.x = us[0] | (us[1] << 16);
        pk.y = us[2] | (us[3] << 16);
        *(uint2*)&xo[mt * 16 + (g4 << 2)] = pk;
    }
}

// ---------------------------------------------------------------- K6 v3: tanh-sum over r | route role (out_w)
__global__ __launch_bounds__(256) void k6_out(const __hip_bfloat16* __restrict__ xin,
                                              const float* __restrict__ gains,
                                              const float* __restrict__ control,
                                              const float* __restrict__ router,
                                              float* __restrict__ out,
                                              float* __restrict__ out_w) {
    __shared__ float gabs[N_RES];
    int bid = blockIdx.x;                 // 384 = 256 tanh-sum + 128 route
    int tid = threadIdx.x;
    if (bid >= 256) {
        int idx = (bid - 256) * 256 + tid;
        int f  = idx % CTRL;
        int r  = (idx / CTRL) % N_RES;
        int bn = idx / (CTRL * N_RES);
        float s = 0.f;
        #pragma unroll
        for (int c = 0; c < CPD; ++c)
            s += control[(bn * CPD + c) * CTRL + f] * router[c * N_RES + r];
        out_w[idx] = s;
        return;
    }
    int bn = bid >> 5, oslab = bid & 31;
    int jo = tid & 31;
    int oc = tid >> 5;
    int ocol = oslab * 8 + oc;
    if (tid < 32) gabs[tid] = fabsf(gains[tid]);
    __syncthreads();
    float acc[4] = {0.f, 0.f, 0.f, 0.f};
    #pragma unroll 4
    for (int r = 0; r < N_RES; ++r) {
        const unsigned int* p = (const unsigned int*)(xin + ((size_t)(bn * N_RES + r) * 256 + ocol) * 128 + jo * 4);
        unsigned int w0 = p[0], w1 = p[1];
        float g = gabs[r];
        unsigned short h0 = (unsigned short)(w0 & 0xffff), h1 = (unsigned short)(w0 >> 16);
        unsigned short h2 = (unsigned short)(w1 & 0xffff), h3 = (unsigned short)(w1 >> 16);
        acc[0] += tanhf(__bfloat162float(*(__hip_bfloat16*)&h0) * g);
        acc[1] += tanhf(__bfloat162float(*(__hip_bfloat16*)&h1) * g);
        acc[2] += tanhf(__bfloat162float(*(__hip_bfloat16*)&h2) * g);
        acc[3] += tanhf(__bfloat162float(*(__hip_bfloat16*)&h3) * g);
    }
    #pragma unroll
    for (int jj = 0; jj < 4; ++jj)
        out[(size_t)bn * N_SAMPLES + (jo * 4 + jj) * 256 + ocol] = acc[jj];
}

// ---------------------------------------------------------------- launch
extern "C" void kernel_launch(void* const* d_in, const int* in_sizes, int n_in,
                              void* d_out, int out_size, void* d_ws, size_t ws_size,
                              hipStream_t stream) {
    const float* control = (const float*)d_in[0];
    const float* defo    = (const float*)d_in[1];
    const float* router  = (const float*)d_in[2];
    const float* gains   = (const float*)d_in[3];
    const float* amp     = (const float*)d_in[4];
    const float* phase   = (const float*)d_in[5];
    const float* decay   = (const float*)d_in[6];
    const float* noise   = (const float*)d_in[7];

    float* out_summed = (float*)d_out;
    float* out_w      = (float*)d_out + NBN * N_SAMPLES;

    // ws layout:
    //  [0, 8MB): Gbf (k3->k5m)
    //  [8MB, +4KB): normp (k1m->k3)
    //  [16MB, 32.8MB): res_raw f32 (k1m->k3); xout bf16 alias (k5m->k6)
    char* ws = (char*)d_ws;
    short* Gbf = (short*)ws;
    float* normp = (float*)(ws + 8388608);
    char* slot1 = ws + 16777216;
    float* res_raw = (float*)slot1;
    __hip_bfloat16* xout = (__hip_bfloat16*)slot1;

    k1m<<<1024, 256, 0, stream>>>(amp, phase, decay, res_raw, normp);
    k3_impconv<<<512, 256, 0, stream>>>(res_raw, normp, noise, (uint4*)Gbf);
    k5m<<<1024, 256, 0, stream>>>(Gbf, control, router, defo, xout);
    k6_out<<<384, 256, 0, stream>>>(xout, gains, control, router, out_summed, out_w);
}

// Round 13
// 107.075 us; speedup vs baseline: 1.6486x; 1.0232x over previous
//
#include <hip/hip_runtime.h>
#include <hip/hip_bf16.h>
#include <math.h>

#define N_SAMPLES 32768
#define STEP 256
#define N_FRAMES 128
#define N_COEFFS 257
#define KT 576            // stacked K: 288 (cos) + 288 (sin)
#define NKS 18            // K-steps of 32
#define CPD 16
#define N_RES 32
#define EXPR 4
#define CTRL 128
#define NBN 8
#define PI_F 3.14159265358979323846f

typedef __attribute__((ext_vector_type(8))) short bf16x8;
typedef __attribute__((ext_vector_type(4))) float f32x4;

__device__ __forceinline__ unsigned short f2bf(float x) {
    __hip_bfloat16 h = __float2bfloat16(x);
    return *(unsigned short*)&h;
}

// ---------------------------------------------------------------- K1m v4: self-contained MFMA GEMM, double-buffered B-gen
__global__ __launch_bounds__(256) void k1m(const float* __restrict__ amp,
                                           const float* __restrict__ phase,
                                           const float* __restrict__ decay,
                                           float* __restrict__ res_raw,
                                           float* __restrict__ normp) {
    __shared__ __align__(16) short Bs[2][2048];   // double-buffered 64j x 32k bf16
    __shared__ __align__(16) float Pl[KT];
    __shared__ __align__(16) float Zl[KT];
    __shared__ __align__(16) float Ll[KT];
    __shared__ float red[256];
    int tid = threadIdx.x;
    int l = tid & 63, w = tid >> 6;
    int bid = blockIdx.x;             // 1024, XCD-swizzled on re
    int x = bid & 7, m = bid >> 3;
    int re = x * 16 + (m >> 3);
    int sub = m & 7;
    int bx = sub >> 1, jb = sub & 1;
    int r = re >> 2, e = re & 3;

    // ---- per-block param compute
    for (int k = tid; k < KT; k += 256) {
        int kk = (k < 288) ? k : k - 288;
        float P = 0.f, Z = 0.f, L2v = 0.f;
        if (kk < N_COEFFS) {
            int src = (r * N_COEFFS + kk) * EXPR + e;
            float mm = fabsf(amp[src]) + 1e-12f;
            float ph = tanhf(phase[src]) * PI_F;
            float sg = 1.0f / (1.0f + expf(-decay[src]));
            float d  = 0.5f + 0.45f * sg;
            float wk = (kk == 0 || kk == 256) ? (1.0f / 512.0f) : (2.0f / 512.0f);
            float c  = (k < 288) ? (wk * mm * cosf(ph)) : (-wk * mm * sinf(ph));
            float sgn = (kk & 1) ? -1.f : 1.f;
            P = c * (d + sgn);
            Z = c * d;
            L2v = log2f(d);
        }
        Pl[k] = P; Zl[k] = Z; Ll[k] = L2v;
    }
    __syncthreads();

    // ---- twiddle recurrence state
    int o = (bx * 4 + w) * 16 + (l & 15);
    int g4v = l >> 4;
    float cb[8], sb[8], cc[8], sc[8];
    #pragma unroll
    for (int ee = 0; ee < 8; ++ee) {
        int delta = ((ee >> 2) << 4) + (g4v << 2) + (ee & 3);
        float ang = (float)((delta * o) & 511) * (2.0f * PI_F / 512.0f);
        sincosf(ang, &sb[ee], &cb[ee]);
        cc[ee] = cb[ee]; sc[ee] = sb[ee];
    }
    float rc, rs;
    {
        float ang = (float)((32 * o) & 511) * (2.0f * PI_F / 512.0f);
        sincosf(ang, &rs, &rc);
    }

    int gj = tid >> 2;
    int gg = tid & 3;
    int jf = jb * 64 + gj;
    float jf_f = (float)jf;

    f32x4 acc[4] = {{0.f,0.f,0.f,0.f},{0.f,0.f,0.f,0.f},{0.f,0.f,0.f,0.f},{0.f,0.f,0.f,0.f}};
    int boff = (l & 15) * 32 + (l >> 4) * 8;

    auto GEN = [&](int s, int buf) {
        int kb = s * 32 + gg * 4;
        f32x4 p0 = *(const f32x4*)&Pl[kb];
        f32x4 p1 = *(const f32x4*)&Pl[kb + 16];
        f32x4 z0 = *(const f32x4*)&Zl[kb];
        f32x4 z1 = *(const f32x4*)&Zl[kb + 16];
        f32x4 l0 = *(const f32x4*)&Ll[kb];
        f32x4 l1 = *(const f32x4*)&Ll[kb + 16];
        bf16x8 vv;
        #pragma unroll
        for (int q = 0; q < 4; ++q) {
            float v0 = (jf == 0) ? z0[q] : p0[q] * exp2f(jf_f * l0[q]);
            float v1 = (jf == 0) ? z1[q] : p1[q] * exp2f(jf_f * l1[q]);
            vv[q]     = (short)f2bf(v0);
            vv[4 + q] = (short)f2bf(v1);
        }
        *(bf16x8*)&Bs[buf][gj * 32 + gg * 8] = vv;
    };

    GEN(0, 0);
    __syncthreads();
    #pragma unroll
    for (int s = 0; s < NKS; ++s) {
        if (s < NKS - 1) GEN(s + 1, (s + 1) & 1);   // write other buffer
        if (s == 9) {
            #pragma unroll
            for (int ee = 0; ee < 8; ++ee) { cc[ee] = cb[ee]; sc[ee] = sb[ee]; }
        }
        bf16x8 af;
        #pragma unroll
        for (int ee = 0; ee < 8; ++ee)
            af[ee] = (short)f2bf((s < 9) ? cc[ee] : sc[ee]);
        if (s != 8 && s != NKS - 1) {
            #pragma unroll
            for (int ee = 0; ee < 8; ++ee) {
                float t = cc[ee] * rc - sc[ee] * rs;
                sc[ee] = fmaf(cc[ee], rs, sc[ee] * rc);
                cc[ee] = t;
            }
        }
        const short* bp = &Bs[s & 1][0];
        #pragma unroll
        for (int jt = 0; jt < 4; ++jt) {
            bf16x8 bf = *(const bf16x8*)(bp + jt * 512 + boff);
            acc[jt] = __builtin_amdgcn_mfma_f32_16x16x32_bf16(af, bf, acc[jt], 0, 0, 0);
        }
        __syncthreads();              // gen(s+1) writes + mfma reads both done
    }

    int otile = bx * 4 + w;
    int o0 = otile * 16 + ((l >> 4) & 3) * 4;
    int jbase = jb * 64 + (l & 15);
    float s2 = 0.f;
    #pragma unroll
    for (int jt = 0; jt < 4; ++jt) {
        int j = jbase + jt * 16;
        float4 v = make_float4(acc[jt][0], acc[jt][1], acc[jt][2], acc[jt][3]);
        s2 += v.x * v.x + v.y * v.y + v.z * v.z + v.w * v.w;
        *(float4*)&res_raw[(size_t)re * N_SAMPLES + j * STEP + o0] = v;
    }
    red[tid] = s2;
    __syncthreads();
    for (int st = 128; st > 0; st >>= 1) {
        if (tid < st) red[tid] += red[tid + st];
        __syncthreads();
    }
    if (tid == 0) normp[re * 8 + bx * 2 + jb] = red[0];
}

// ---------------------------------------------------------------- K3: sliding-register FIR (+inline norm finalize)
__global__ __launch_bounds__(256) void k3_impconv(const float* __restrict__ res_raw,
                                                  const float* __restrict__ normp,
                                                  const float* __restrict__ noise,
                                                  uint4* __restrict__ Gbf_q) {
    __shared__ __align__(16) float st[8320];
    __shared__ __align__(16) float imp[128];
    int bid = blockIdx.x;                 // 512, XCD-swizzled on r
    int r  = (bid & 7) * 4 + ((bid >> 3) & 3);
    int t2 = bid >> 5;
    int e  = t2 & 3;
    int kt = t2 >> 2;
    int tid = threadIdx.x;
    int re = r * 4 + e;
    float ns = 0.f;
    #pragma unroll
    for (int i = 0; i < 8; ++i) ns += normp[re * 8 + i];
    float inv = 1.0f / (sqrtf(ns) + 1e-8f);
    if (tid < 128)
        imp[tid] = (0.54f - 0.46f * cosf((2.0f * PI_F / 128.0f) * (float)tid)) * noise[tid];
    const float* rp = res_raw + (size_t)re * N_SAMPLES;
    int gbase = kt * 8192 - 127;
    for (int i = tid; i < 8320; i += 256) {
        int g = gbase + i;
        st[i] = (g >= 0 && g < N_SAMPLES) ? rp[g] * inv : 0.f;
    }
    __syncthreads();

    int jg = tid >> 6;
    int o0 = (tid & 63) * 4;
    int jl[8];
    #pragma unroll
    for (int hh = 0; hh < 4; ++hh) {
        int h = jg * 4 + hh;
        int j0 = ((h >> 1) & 1) * 16 + (h >> 2) * 4 + (h & 1) * 2;
        jl[2 * hh] = j0;
        jl[2 * hh + 1] = j0 + 1;
    }
    float4 cur[8];
    float acc[8][4] = {};
    #pragma unroll
    for (int w = 0; w < 8; ++w)
        cur[w] = *(const float4*)&st[jl[w] * 256 + o0];

    for (int v = 0; v < 128; v += 4) {
        float4 im = *(const float4*)&imp[124 - v];
        float wt[4] = {im.w, im.z, im.y, im.x};
        #pragma unroll
        for (int w = 0; w < 8; ++w) {
            float4 nx = *(const float4*)&st[jl[w] * 256 + o0 + v + 4];
            float win[8] = {cur[w].x, cur[w].y, cur[w].z, cur[w].w, nx.x, nx.y, nx.z, nx.w};
            #pragma unroll
            for (int k = 0; k < 4; ++k)
                #pragma unroll
                for (int d = 0; d < 4; ++d)
                    acc[w][d] = fmaf(wt[k], win[d + k], acc[w][d]);
            cur[w] = nx;
        }
    }

    size_t rowb = (((size_t)(r * 4 + e) * 4 + kt) * 256 + o0) * 4;
    #pragma unroll
    for (int d = 0; d < 4; ++d) {
        uint4 outv;
        outv.x = (unsigned int)f2bf(acc[0][d]) | ((unsigned int)f2bf(acc[1][d]) << 16);
        outv.y = (unsigned int)f2bf(acc[2][d]) | ((unsigned int)f2bf(acc[3][d]) << 16);
        outv.z = (unsigned int)f2bf(acc[4][d]) | ((unsigned int)f2bf(acc[5][d]) << 16);
        outv.w = (unsigned int)f2bf(acc[6][d]) | ((unsigned int)f2bf(acc[7][d]) << 16);
        Gbf_q[rowb + (size_t)d * 4 + jg] = outv;
    }
}

// ---------------------------------------------------------------- K5m v5: MFMA Toeplitz conv, G staged once, both bnh halves
__global__ __launch_bounds__(256) void k5m(const short* __restrict__ Gbf,
                                           const float* __restrict__ control,
                                           const float* __restrict__ router,
                                           const float* __restrict__ defo,
                                           __hip_bfloat16* __restrict__ xout) {
    const int mt_of[20] = {0,1,2,2,3,3,4,4,4,5,5,5,6,6,6,6,7,7,7,7};
    const int kt_of[20] = {0,0,0,1,0,1,0,1,2,0,1,2,0,1,2,3,0,1,2,3};
    __shared__ __align__(16) short Gs[8192];       // 16KB
    __shared__ __align__(16) float tab[4][130][4]; // 8320B
    __shared__ __align__(16) float wrow[4][128];   // 2KB
    int tid = threadIdx.x;
    int bid = blockIdx.x;                           // 512 = r(32, XCD-swz) x on(16)
    int r   = (bid & 7) * 4 + ((bid >> 3) & 3);
    int on  = bid >> 5;

    // ---- stage G tiles once (shared across both bnh halves)
    #pragma unroll
    for (int it = 0; it < 4; ++it) {
        int c = it * 256 + tid;
        int ekt = c >> 6;
        int o = (c >> 2) & 15;
        int h = c & 3;
        const short* src = Gbf + (((size_t)(r * 16 + ekt) * 256 + on * 16 + o) * 32 + h * 8);
        __builtin_amdgcn_global_load_lds(
            (__attribute__((address_space(1))) const void*)src,
            (__attribute__((address_space(3))) void*)(&Gs[c * 8]), 16, 0, 0);
    }

    int l = tid & 63, w = tid >> 6;
    int n = l & 15, g4 = l >> 4;
    int ocol = on * 16 + n;
    int c = (on < 8) ? -1 : 0;
    float wg = (((float)ocol + 0.5f) * (1.0f / 256.0f) - 0.5f) - (float)c;

    bf16x8 bfr[4][4];
    bool bfr_loaded = false;

    for (int bnh = 0; bnh < 2; ++bnh) {
        // ---- W rows + softmax tab for this bn-half
        for (int i = tid; i < 512; i += 256) {
            int bnl = i >> 7, f = i & 127;
            int bn = bnh * 4 + bnl;
            float s = 0.f;
            #pragma unroll
            for (int cc = 0; cc < CPD; ++cc)
                s += control[(bn * CPD + cc) * CTRL + f] * router[cc * N_RES + r];
            wrow[bnl][f] = s;
        }
        for (int i = tid; i < 512; i += 256) {
            int bnl = i >> 7, f = i & 127;
            int bn = bnh * 4 + bnl;
            float v[EXPR]; float mx = -1e30f;
            #pragma unroll
            for (int e = 0; e < EXPR; ++e) {
                float xv = defo[(bn * EXPR + e) * CTRL + f] + (e == 0 ? 1.0f : 0.0f);
                v[e] = xv; mx = fmaxf(mx, xv);
            }
            float sum = 0.f;
            #pragma unroll
            for (int e = 0; e < EXPR; ++e) { v[e] = expf(v[e] - mx); sum += v[e]; }
            float is = 1.0f / sum;
            f32x4 tv = {v[0] * is, v[1] * is, v[2] * is, v[3] * is};
            *(f32x4*)&tab[bnl][f + 1][0] = tv;
        }
        if (tid < 8) {
            int bnl = tid & 3, hi = tid >> 2;
            int bn = bnh * 4 + bnl;
            int f = hi ? 127 : 0;
            int jj = hi ? 129 : 0;
            float v[EXPR]; float mx = -1e30f;
            #pragma unroll
            for (int e = 0; e < EXPR; ++e) {
                float xv = defo[(bn * EXPR + e) * CTRL + f] + (e == 0 ? 1.0f : 0.0f);
                v[e] = xv; mx = fmaxf(mx, xv);
            }
            float sum = 0.f;
            #pragma unroll
            for (int e = 0; e < EXPR; ++e) { v[e] = expf(v[e] - mx); sum += v[e]; }
            float is = 1.0f / sum;
            f32x4 tv = {v[0] * is, v[1] * is, v[2] * is, v[3] * is};
            *(f32x4*)&tab[bnl][jj][0] = tv;
        }
        __syncthreads();   // wrow/tab ready; (bnh==0) also covers Gs staging

        if (!bfr_loaded) {
            #pragma unroll
            for (int e = 0; e < 4; ++e)
                #pragma unroll
                for (int kt = 0; kt < 4; ++kt)
                    bfr[e][kt] = *(const bf16x8*)&Gs[(e * 4 + kt) * 512 + n * 32 + g4 * 8];
            bfr_loaded = true;
        }

        int bn = bnh * 4 + w;
        bf16x8 wfrag[8];
        #pragma unroll
        for (int b = 0; b < 8; ++b) {
            bf16x8 v;
            #pragma unroll
            for (int ee = 0; ee < 8; ++ee) {
                int diff = b * 16 + n - ((ee >> 2) << 4) - (g4 << 2) - (ee & 3);
                float val = (diff >= 0) ? wrow[w][diff] : 0.f;
                v[ee] = (short)f2bf(val);
            }
            wfrag[b] = v;
        }

        f32x4 acc[4][8] = {};
        #pragma unroll
        for (int pr = 0; pr < 20; ++pr) {
            int mt = mt_of[pr], kt = kt_of[pr];
            int b = mt - 2 * kt;
            #pragma unroll
            for (int e = 0; e < 4; ++e)
                acc[e][mt] = __builtin_amdgcn_mfma_f32_16x16x32_bf16(wfrag[b], bfr[e][kt], acc[e][mt], 0, 0, 0);
        }

        __hip_bfloat16* xo = xout + ((size_t)(bn * N_RES + r) * 256 + ocol) * 128;
        #pragma unroll
        for (int mt = 0; mt < 8; ++mt) {
            int base = mt * 16 + (g4 << 2) + c + 1;
            f32x4 tv[5];
            #pragma unroll
            for (int q = 0; q < 5; ++q)
                tv[q] = *(const f32x4*)&tab[w][base + q][0];
            unsigned int us[4];
            #pragma unroll
            for (int q = 0; q < 4; ++q) {
                float xv = 0.f;
                #pragma unroll
                for (int e = 0; e < 4; ++e) {
                    float de = fmaf(wg, tv[q + 1][e] - tv[q][e], tv[q][e]);
                    xv = fmaf(de, acc[e][mt][q], xv);
                }
                us[q] = (unsigned int)f2bf(xv);
            }
            uint2 pk;
            pk.x = us[0] | (us[1] << 16);
            pk.y = us[2] | (us[3] << 16);
            *(uint2*)&xo[mt * 16 + (g4 << 2)] = pk;
        }
        __syncthreads();   // protect tab/wrow rewrite for next half
    }
}

// ---------------------------------------------------------------- K6: tanh-sum over r | route role (out_w)
__global__ __launch_bounds__(256) void k6_out(const __hip_bfloat16* __restrict__ xin,
                                              const float* __restrict__ gains,
                                              const float* __restrict__ control,
                                              const float* __restrict__ router,
                                              float* __restrict__ out,
                                              float* __restrict__ out_w) {
    __shared__ float gabs[N_RES];
    int bid = blockIdx.x;                 // 384 = 256 tanh-sum + 128 route
    int tid = threadIdx.x;
    if (bid >= 256) {
        int idx = (bid - 256) * 256 + tid;
        int f  = idx % CTRL;
        int r  = (idx / CTRL) % N_RES;
        int bn = idx / (CTRL * N_RES);
        float s = 0.f;
        #pragma unroll
        for (int c = 0; c < CPD; ++c)
            s += control[(bn * CPD + c) * CTRL + f] * router[c * N_RES + r];
        out_w[idx] = s;
        return;
    }
    int bn = bid >> 5, oslab = bid & 31;
    int jo = tid & 31;
    int oc = tid >> 5;
    int ocol = oslab * 8 + oc;
    if (tid < 32) gabs[tid] = fabsf(gains[tid]);
    __syncthreads();
    float acc[4] = {0.f, 0.f, 0.f, 0.f};
    #pragma unroll 4
    for (int r = 0; r < N_RES; ++r) {
        const unsigned int* p = (const unsigned int*)(xin + ((size_t)(bn * N_RES + r) * 256 + ocol) * 128 + jo * 4);
        unsigned int w0 = p[0], w1 = p[1];
        float g = gabs[r];
        unsigned short h0 = (unsigned short)(w0 & 0xffff), h1 = (unsigned short)(w0 >> 16);
        unsigned short h2 = (unsigned short)(w1 & 0xffff), h3 = (unsigned short)(w1 >> 16);
        acc[0] += tanhf(__bfloat162float(*(__hip_bfloat16*)&h0) * g);
        acc[1] += tanhf(__bfloat162float(*(__hip_bfloat16*)&h1) * g);
        acc[2] += tanhf(__bfloat162float(*(__hip_bfloat16*)&h2) * g);
        acc[3] += tanhf(__bfloat162float(*(__hip_bfloat16*)&h3) * g);
    }
    #pragma unroll
    for (int jj = 0; jj < 4; ++jj)
        out[(size_t)bn * N_SAMPLES + (jo * 4 + jj) * 256 + ocol] = acc[jj];
}

// ---------------------------------------------------------------- launch
extern "C" void kernel_launch(void* const* d_in, const int* in_sizes, int n_in,
                              void* d_out, int out_size, void* d_ws, size_t ws_size,
                              hipStream_t stream) {
    const float* control = (const float*)d_in[0];
    const float* defo    = (const float*)d_in[1];
    const float* router  = (const float*)d_in[2];
    const float* gains   = (const float*)d_in[3];
    const float* amp     = (const float*)d_in[4];
    const float* phase   = (const float*)d_in[5];
    const float* decay   = (const float*)d_in[6];
    const float* noise   = (const float*)d_in[7];

    float* out_summed = (float*)d_out;
    float* out_w      = (float*)d_out + NBN * N_SAMPLES;

    // ws layout:
    //  [0, 8MB): Gbf (k3->k5m)
    //  [8MB, +4KB): normp (k1m->k3)
    //  [16MB, 32.8MB): res_raw f32 (k1m->k3); xout bf16 alias (k5m->k6)
    char* ws = (char*)d_ws;
    short* Gbf = (short*)ws;
    float* normp = (float*)(ws + 8388608);
    char* slot1 = ws + 16777216;
    float* res_raw = (float*)slot1;
    __hip_bfloat16* xout = (__hip_bfloat16*)slot1;

    k1m<<<1024, 256, 0, stream>>>(amp, phase, decay, res_raw, normp);
    k3_impconv<<<512, 256, 0, stream>>>(res_raw, normp, noise, (uint4*)Gbf);
    k5m<<<512, 256, 0, stream>>>(Gbf, control, router, defo, xout);
    k6_out<<<384, 256, 0, stream>>>(xout, gains, control, router, out_summed, out_w);
}